// Round 10
// baseline (3367.905 us; speedup 1.0000x reference)
//
#include <hip/hip_runtime.h>
#include <math.h>

#define TT 4096
#define HH 768
#define NHEAD 12
#define HDIM 64
#define NEXP 8
#define FDIM 1536
#define CAP 640
#define SEQ 2048
#define VOCAB 32000

typedef __attribute__((ext_vector_type(4))) float f32x4;
typedef __attribute__((ext_vector_type(8))) short bf16x8;

__device__ __forceinline__ unsigned short f2bf(float f) {
    unsigned int u = __float_as_uint(f);
    unsigned int r = u + 0x7fffu + ((u >> 16) & 1u);
    return (unsigned short)(r >> 16);
}

// --------- input_ids normalize (robust to int32 or int64 host layout) ---------
__global__ __launch_bounds__(256) void k_ids(const int* __restrict__ in, int* __restrict__ outi) {
    __shared__ int is64;
    if (threadIdx.x == 0) {
        int o = 0;
        for (int i = 1; i < 128; i += 2) o |= in[i];
        is64 = (o == 0) ? 1 : 0;
    }
    __syncthreads();
    const int stride = is64 ? 2 : 1;
    for (int t = threadIdx.x + blockIdx.x * 256; t < TT; t += gridDim.x * 256) {
        int v = in[t * stride];
        v = v < 0 ? 0 : (v >= VOCAB ? VOCAB - 1 : v);
        outi[t] = v;
    }
}

__global__ __launch_bounds__(192) void k_embed(const int* __restrict__ ids, const float* __restrict__ ew,
                                               float* __restrict__ h) {
    const int t = blockIdx.x;
    const int id = ids[t];
    const float4* src = reinterpret_cast<const float4*>(ew + (size_t)id * HH);
    float4* dst = reinterpret_cast<float4*>(h + (size_t)t * HH);
    dst[threadIdx.x] = src[threadIdx.x];
}

__global__ __launch_bounds__(64) void k_ln(const float* __restrict__ x, const float* __restrict__ g,
                                           const float* __restrict__ b, float* __restrict__ y) {
    const int t = blockIdx.x;
    const int lane = threadIdx.x;
    const float* row = x + (size_t)t * HH;
    float v[12];
    float s = 0.f, sq = 0.f;
#pragma unroll
    for (int i = 0; i < 12; i++) {
        float f = row[lane + (i << 6)];
        v[i] = f; s += f; sq += f * f;
    }
#pragma unroll
    for (int off = 32; off; off >>= 1) { s += __shfl_xor(s, off); sq += __shfl_xor(sq, off); }
    const float mean = s * (1.f / 768.f);
    float var = sq * (1.f / 768.f) - mean * mean;
    var = fmaxf(var, 0.f);
    const float rstd = rsqrtf(var + 1e-5f);
    float* yr = y + (size_t)t * HH;
#pragma unroll
    for (int i = 0; i < 12; i++) {
        const int d = lane + (i << 6);
        yr[d] = (v[i] - mean) * rstd * g[d] + b[d];
    }
}

// ---------------- fp32 -> bf16 convert (8 elems/thread) ----------------
__global__ __launch_bounds__(256) void k_tobf(const float* __restrict__ in, unsigned short* __restrict__ outb,
                                              const int n8) {
    const int i = blockIdx.x * 256 + threadIdx.x;
    if (i >= n8) return;
    const float4 x0 = *reinterpret_cast<const float4*>(in + (size_t)i * 8);
    const float4 x1 = *reinterpret_cast<const float4*>(in + (size_t)i * 8 + 4);
    ushort4 o0, o1;
    o0.x = f2bf(x0.x); o0.y = f2bf(x0.y); o0.z = f2bf(x0.z); o0.w = f2bf(x0.w);
    o1.x = f2bf(x1.x); o1.y = f2bf(x1.y); o1.z = f2bf(x1.z); o1.w = f2bf(x1.w);
    *reinterpret_cast<ushort4*>(outb + (size_t)i * 8) = o0;
    *reinterpret_cast<ushort4*>(outb + (size_t)i * 8 + 4) = o1;
}

// ---------------- bf16-MFMA GEMM 64x64 (proven): C = A(MxK) * B ----------------
template<bool BT, bool XMAJ, bool BIAS, bool GELU, bool RESID, typename AT, typename OT>
__global__ __launch_bounds__(256) void k_gemm(
    const AT* __restrict__ A, const float* __restrict__ B,
    const float* __restrict__ bias, const float* __restrict__ resid,
    OT* __restrict__ C,
    const int M, const int N, const int K,
    const long long eA, const long long eB, const long long eBias, const long long eC)
{
    const int e = blockIdx.z;
    A += e * eA; B += e * eB; C += e * eC;
    if (BIAS) bias += e * eBias;

    __shared__ __align__(16) short As[64][40];
    __shared__ __align__(16) short Bs[64][40];

    const int tid = threadIdx.x;
    const int lane = tid & 63;
    const int w = tid >> 6;
    const int n0 = (XMAJ ? blockIdx.y : blockIdx.x) * 64;
    const int m0 = (XMAJ ? blockIdx.x : blockIdx.y) * 64;

    f32x4 zero = {0.f, 0.f, 0.f, 0.f};
    f32x4 acc[4];
#pragma unroll
    for (int c = 0; c < 4; c++) acc[c] = zero;

    const int ar = tid >> 2;
    const int ak = (tid & 3) << 3;
    const AT* aptr = A + (size_t)(m0 + ar) * K + ak;

    for (int k0 = 0; k0 < K; k0 += 32) {
        if constexpr (sizeof(AT) == 4) {
            const float* ap = reinterpret_cast<const float*>(aptr) + k0;
            const float4 x0 = *reinterpret_cast<const float4*>(ap);
            const float4 x1 = *reinterpret_cast<const float4*>(ap + 4);
            short* d = &As[ar][ak];
            d[0] = (short)f2bf(x0.x); d[1] = (short)f2bf(x0.y);
            d[2] = (short)f2bf(x0.z); d[3] = (short)f2bf(x0.w);
            d[4] = (short)f2bf(x1.x); d[5] = (short)f2bf(x1.y);
            d[6] = (short)f2bf(x1.z); d[7] = (short)f2bf(x1.w);
        } else {
            const unsigned short* ap = reinterpret_cast<const unsigned short*>(aptr) + k0;
            *reinterpret_cast<int4*>(&As[ar][ak]) = *reinterpret_cast<const int4*>(ap);
        }
        if constexpr (BT) {
            const float* bp = B + (size_t)(n0 + ar) * K + k0 + ak;
            const float4 x0 = *reinterpret_cast<const float4*>(bp);
            const float4 x1 = *reinterpret_cast<const float4*>(bp + 4);
            short* d = &Bs[ar][ak];
            d[0] = (short)f2bf(x0.x); d[1] = (short)f2bf(x0.y);
            d[2] = (short)f2bf(x0.z); d[3] = (short)f2bf(x0.w);
            d[4] = (short)f2bf(x1.x); d[5] = (short)f2bf(x1.y);
            d[6] = (short)f2bf(x1.z); d[7] = (short)f2bf(x1.w);
        } else {
            const int kk = tid >> 6;
            const int nn = tid & 63;
#pragma unroll
            for (int it = 0; it < 8; it++) {
                const int kl = kk + (it << 2);
                Bs[nn][kl] = (short)f2bf(B[(size_t)(k0 + kl) * N + n0 + nn]);
            }
        }
        __syncthreads();
        const bf16x8 af = *reinterpret_cast<const bf16x8*>(&As[(w << 4) + (lane & 15)][(lane >> 4) << 3]);
#pragma unroll
        for (int c = 0; c < 4; c++) {
            const bf16x8 bfr = *reinterpret_cast<const bf16x8*>(&Bs[(c << 4) + (lane & 15)][(lane >> 4) << 3]);
            acc[c] = __builtin_amdgcn_mfma_f32_16x16x32_bf16(af, bfr, acc[c], 0, 0, 0);
        }
        __syncthreads();
    }

    const int rb = (w << 4) + ((lane >> 4) << 2);
    const int cl = lane & 15;
#pragma unroll
    for (int c = 0; c < 4; c++) {
        const int col = n0 + (c << 4) + cl;
        float bv = 0.f;
        if constexpr (BIAS) bv = bias[col];
#pragma unroll
        for (int r = 0; r < 4; r++) {
            const int lrow = m0 + rb + r;
            float v = acc[c][r] + bv;
            if constexpr (GELU) v = 0.5f * v * (1.f + erff(v * 0.70710678118654752f));
            if constexpr (RESID) v += resid[(size_t)lrow * N + col];
            if constexpr (sizeof(OT) == 2) {
                C[(size_t)lrow * N + col] = (OT)f2bf(v);
            } else {
                C[(size_t)lrow * N + col] = v;
            }
        }
    }
}

// ---------------- bf16-MFMA GEMM 128x128 fp32-in (head fallback): C = A*B^T ----------------
__global__ __launch_bounds__(256) void k_gemm128(
    const float* __restrict__ A, const float* __restrict__ B, float* __restrict__ C,
    const int M, const int N, const int K)
{
    __shared__ __align__(16) short As[128][40];
    __shared__ __align__(16) short Bs[128][40];

    const int tid = threadIdx.x;
    const int lane = tid & 63;
    const int w = tid >> 6;
    const int wm = w >> 1, wn = w & 1;
    const int m0 = blockIdx.x * 128, n0 = blockIdx.y * 128;

    f32x4 zero = {0.f, 0.f, 0.f, 0.f};
    f32x4 acc[4][4];
#pragma unroll
    for (int mi = 0; mi < 4; mi++)
#pragma unroll
        for (int ni = 0; ni < 4; ni++) acc[mi][ni] = zero;

    const int srow = tid >> 1;
    const int sk = (tid & 1) << 4;
    const float* aptr = A + (size_t)(m0 + srow) * K + sk;
    const float* bptr = B + (size_t)(n0 + srow) * K + sk;

    const int kh = (lane >> 4) << 3;
    const int l15 = lane & 15;

    for (int k0 = 0; k0 < K; k0 += 32) {
        {
            const float4 a0 = *reinterpret_cast<const float4*>(aptr + k0);
            const float4 a1 = *reinterpret_cast<const float4*>(aptr + k0 + 4);
            const float4 a2 = *reinterpret_cast<const float4*>(aptr + k0 + 8);
            const float4 a3 = *reinterpret_cast<const float4*>(aptr + k0 + 12);
            short* d = &As[srow][sk];
            d[0]  = (short)f2bf(a0.x); d[1]  = (short)f2bf(a0.y);
            d[2]  = (short)f2bf(a0.z); d[3]  = (short)f2bf(a0.w);
            d[4]  = (short)f2bf(a1.x); d[5]  = (short)f2bf(a1.y);
            d[6]  = (short)f2bf(a1.z); d[7]  = (short)f2bf(a1.w);
            d[8]  = (short)f2bf(a2.x); d[9]  = (short)f2bf(a2.y);
            d[10] = (short)f2bf(a2.z); d[11] = (short)f2bf(a2.w);
            d[12] = (short)f2bf(a3.x); d[13] = (short)f2bf(a3.y);
            d[14] = (short)f2bf(a3.z); d[15] = (short)f2bf(a3.w);
            const float4 b0 = *reinterpret_cast<const float4*>(bptr + k0);
            const float4 b1 = *reinterpret_cast<const float4*>(bptr + k0 + 4);
            const float4 b2 = *reinterpret_cast<const float4*>(bptr + k0 + 8);
            const float4 b3 = *reinterpret_cast<const float4*>(bptr + k0 + 12);
            short* e = &Bs[srow][sk];
            e[0]  = (short)f2bf(b0.x); e[1]  = (short)f2bf(b0.y);
            e[2]  = (short)f2bf(b0.z); e[3]  = (short)f2bf(b0.w);
            e[4]  = (short)f2bf(b1.x); e[5]  = (short)f2bf(b1.y);
            e[6]  = (short)f2bf(b1.z); e[7]  = (short)f2bf(b1.w);
            e[8]  = (short)f2bf(b2.x); e[9]  = (short)f2bf(b2.y);
            e[10] = (short)f2bf(b2.z); e[11] = (short)f2bf(b2.w);
            e[12] = (short)f2bf(b3.x); e[13] = (short)f2bf(b3.y);
            e[14] = (short)f2bf(b3.z); e[15] = (short)f2bf(b3.w);
        }
        __syncthreads();
        bf16x8 af[4], bfr[4];
#pragma unroll
        for (int mi = 0; mi < 4; mi++)
            af[mi] = *reinterpret_cast<const bf16x8*>(&As[wm * 64 + mi * 16 + l15][kh]);
#pragma unroll
        for (int ni = 0; ni < 4; ni++)
            bfr[ni] = *reinterpret_cast<const bf16x8*>(&Bs[wn * 64 + ni * 16 + l15][kh]);
#pragma unroll
        for (int mi = 0; mi < 4; mi++)
#pragma unroll
            for (int ni = 0; ni < 4; ni++)
                acc[mi][ni] = __builtin_amdgcn_mfma_f32_16x16x32_bf16(af[mi], bfr[ni], acc[mi][ni], 0, 0, 0);
        __syncthreads();
    }

    const int rb = (lane >> 4) << 2;
    const int cl = lane & 15;
#pragma unroll
    for (int mi = 0; mi < 4; mi++) {
#pragma unroll
        for (int ni = 0; ni < 4; ni++) {
            const int col = n0 + wn * 64 + ni * 16 + cl;
#pragma unroll
            for (int r = 0; r < 4; r++) {
                const int row = m0 + wm * 64 + mi * 16 + rb + r;
                C[(size_t)row * N + col] = acc[mi][ni][r];
            }
        }
    }
}

// ---------------- bf16-MFMA GEMM 128x128, pre-converted bf16 inputs (head fast path) -------
__global__ __launch_bounds__(256) void k_gemm128b(
    const unsigned short* __restrict__ A, const unsigned short* __restrict__ B, float* __restrict__ C,
    const int M, const int N, const int K)
{
    __shared__ __align__(16) short As[128][40];
    __shared__ __align__(16) short Bs[128][40];

    const int tid = threadIdx.x;
    const int lane = tid & 63;
    const int w = tid >> 6;
    const int wm = w >> 1, wn = w & 1;
    const int m0 = blockIdx.x * 128, n0 = blockIdx.y * 128;

    f32x4 zero = {0.f, 0.f, 0.f, 0.f};
    f32x4 acc[4][4];
#pragma unroll
    for (int mi = 0; mi < 4; mi++)
#pragma unroll
        for (int ni = 0; ni < 4; ni++) acc[mi][ni] = zero;

    const int srow = tid >> 1;
    const int sk = (tid & 1) << 4;
    const unsigned short* aptr = A + (size_t)(m0 + srow) * K + sk;
    const unsigned short* bptr = B + (size_t)(n0 + srow) * K + sk;

    const int kh = (lane >> 4) << 3;
    const int l15 = lane & 15;

    for (int k0 = 0; k0 < K; k0 += 32) {
        {
            const int4* a4 = reinterpret_cast<const int4*>(aptr + k0);
            *reinterpret_cast<int4*>(&As[srow][sk]) = a4[0];
            *reinterpret_cast<int4*>(&As[srow][sk + 8]) = a4[1];
            const int4* b4 = reinterpret_cast<const int4*>(bptr + k0);
            *reinterpret_cast<int4*>(&Bs[srow][sk]) = b4[0];
            *reinterpret_cast<int4*>(&Bs[srow][sk + 8]) = b4[1];
        }
        __syncthreads();
        bf16x8 af[4], bfr[4];
#pragma unroll
        for (int mi = 0; mi < 4; mi++)
            af[mi] = *reinterpret_cast<const bf16x8*>(&As[wm * 64 + mi * 16 + l15][kh]);
#pragma unroll
        for (int ni = 0; ni < 4; ni++)
            bfr[ni] = *reinterpret_cast<const bf16x8*>(&Bs[wn * 64 + ni * 16 + l15][kh]);
#pragma unroll
        for (int mi = 0; mi < 4; mi++)
#pragma unroll
            for (int ni = 0; ni < 4; ni++)
                acc[mi][ni] = __builtin_amdgcn_mfma_f32_16x16x32_bf16(af[mi], bfr[ni], acc[mi][ni], 0, 0, 0);
        __syncthreads();
    }

    const int rb = (lane >> 4) << 2;
    const int cl = lane & 15;
#pragma unroll
    for (int mi = 0; mi < 4; mi++) {
#pragma unroll
        for (int ni = 0; ni < 4; ni++) {
            const int col = n0 + wn * 64 + ni * 16 + cl;
#pragma unroll
            for (int r = 0; r < 4; r++) {
                const int row = m0 + wm * 64 + mi * 16 + rb + r;
                C[(size_t)row * N + col] = acc[mi][ni][r];
            }
        }
    }
}

// ---------------- fp32 SGEMM 128x128, BK=16, 8x8 microtile (o proj, L0 experts) --------
template<bool BT, bool BIAS, bool GELU, bool RESID>
__global__ __launch_bounds__(256) void k_sgemm128(
    const float* __restrict__ A, const float* __restrict__ B,
    const float* __restrict__ bias, const float* __restrict__ resid,
    float* __restrict__ C,
    const int M, const int N, const int K,
    const long long eA, const long long eB, const long long eBias, const long long eC)
{
    const int e = blockIdx.z;
    A += e * eA; B += e * eB; C += e * eC;
    if (BIAS) bias += e * eBias;

    __shared__ __align__(16) float As[16][132];
    __shared__ __align__(16) float Bs[16][132];

    const int tid = threadIdx.x;
    const int ty = tid >> 4;
    const int tx = tid & 15;
    const int m0 = blockIdx.x * 128;
    const int n0 = blockIdx.y * 128;

    const int mA = tid >> 1;
    const int kA = (tid & 1) << 3;
    const int kB = tid >> 4;
    const int nB = (tid & 15) << 3;

    float acc[8][8];
#pragma unroll
    for (int r = 0; r < 8; r++)
#pragma unroll
        for (int c = 0; c < 8; c++) acc[r][c] = 0.f;

    for (int k0 = 0; k0 < K; k0 += 16) {
        {
            const float* ap = A + (size_t)(m0 + mA) * K + k0 + kA;
            const float4 x0 = *reinterpret_cast<const float4*>(ap);
            const float4 x1 = *reinterpret_cast<const float4*>(ap + 4);
            As[kA + 0][mA] = x0.x; As[kA + 1][mA] = x0.y;
            As[kA + 2][mA] = x0.z; As[kA + 3][mA] = x0.w;
            As[kA + 4][mA] = x1.x; As[kA + 5][mA] = x1.y;
            As[kA + 6][mA] = x1.z; As[kA + 7][mA] = x1.w;
        }
        if constexpr (BT) {
            const float* bp = B + (size_t)(n0 + mA) * K + k0 + kA;
            const float4 x0 = *reinterpret_cast<const float4*>(bp);
            const float4 x1 = *reinterpret_cast<const float4*>(bp + 4);
            Bs[kA + 0][mA] = x0.x; Bs[kA + 1][mA] = x0.y;
            Bs[kA + 2][mA] = x0.z; Bs[kA + 3][mA] = x0.w;
            Bs[kA + 4][mA] = x1.x; Bs[kA + 5][mA] = x1.y;
            Bs[kA + 6][mA] = x1.z; Bs[kA + 7][mA] = x1.w;
        } else {
            const float* bp = B + (size_t)(k0 + kB) * N + n0 + nB;
            const float4 x0 = *reinterpret_cast<const float4*>(bp);
            const float4 x1 = *reinterpret_cast<const float4*>(bp + 4);
            *reinterpret_cast<float4*>(&Bs[kB][nB]) = x0;
            *reinterpret_cast<float4*>(&Bs[kB][nB + 4]) = x1;
        }
        __syncthreads();
#pragma unroll 4
        for (int k = 0; k < 16; k++) {
            float a[8], b[8];
            *reinterpret_cast<float4*>(&a[0]) = *reinterpret_cast<const float4*>(&As[k][ty << 2]);
            *reinterpret_cast<float4*>(&a[4]) = *reinterpret_cast<const float4*>(&As[k][64 + (ty << 2)]);
            *reinterpret_cast<float4*>(&b[0]) = *reinterpret_cast<const float4*>(&Bs[k][tx << 2]);
            *reinterpret_cast<float4*>(&b[4]) = *reinterpret_cast<const float4*>(&Bs[k][64 + (tx << 2)]);
#pragma unroll
            for (int r = 0; r < 8; r++)
#pragma unroll
                for (int c = 0; c < 8; c++) acc[r][c] += a[r] * b[c];
        }
        __syncthreads();
    }

#pragma unroll
    for (int rh = 0; rh < 2; rh++) {
#pragma unroll
        for (int r = 0; r < 4; r++) {
            const int ri = (rh << 2) + r;
            const int row = m0 + rh * 64 + (ty << 2) + r;
#pragma unroll
            for (int ch = 0; ch < 2; ch++) {
                const int colb = n0 + ch * 64 + (tx << 2);
                float4 v4;
#pragma unroll
                for (int c = 0; c < 4; c++) {
                    const int ci = (ch << 2) + c;
                    float v = acc[ri][ci];
                    if constexpr (BIAS) v += bias[colb + c];
                    if constexpr (GELU) v = 0.5f * v * (1.f + erff(v * 0.70710678118654752f));
                    if constexpr (RESID) v += resid[(size_t)row * N + colb + c];
                    (&v4.x)[c] = v;
                }
                *reinterpret_cast<float4*>(&C[(size_t)row * N + colb]) = v4;
            }
        }
    }
}

// ---------------- fused QKV projection (sgemm128 math, bit-identical chains) ------------
__global__ __launch_bounds__(256) void k_qkv(
    const float* __restrict__ A, const float* __restrict__ qw,
    const float* __restrict__ kw, const float* __restrict__ vw,
    float* __restrict__ q, float* __restrict__ kf, float* __restrict__ vf)
{
    __shared__ __align__(16) float As[16][132];
    __shared__ __align__(16) float Bs[16][132];

    const int x = blockIdx.x;
    const int m0 = blockIdx.y * 128;
    const int K = HH;

    const int tid = threadIdx.x;
    const int ty = tid >> 4;
    const int tx = tid & 15;
    const int mA = tid >> 1;
    const int kA = (tid & 1) << 3;

    const float* arow = A + (size_t)(m0 + mA) * K + kA;
    const float* brow;
    if (x < 6) brow = qw + (size_t)(x * 128 + mA) * K + kA;
    else       brow = (mA < 64 ? kw + (size_t)mA * K : vw + (size_t)(mA - 64) * K) + kA;

    float acc[8][8];
#pragma unroll
    for (int r = 0; r < 8; r++)
#pragma unroll
        for (int c = 0; c < 8; c++) acc[r][c] = 0.f;

    for (int k0 = 0; k0 < K; k0 += 16) {
        {
            const float4 x0 = *reinterpret_cast<const float4*>(arow + k0);
            const float4 x1 = *reinterpret_cast<const float4*>(arow + k0 + 4);
            As[kA + 0][mA] = x0.x; As[kA + 1][mA] = x0.y;
            As[kA + 2][mA] = x0.z; As[kA + 3][mA] = x0.w;
            As[kA + 4][mA] = x1.x; As[kA + 5][mA] = x1.y;
            As[kA + 6][mA] = x1.z; As[kA + 7][mA] = x1.w;
        }
        {
            const float4 x0 = *reinterpret_cast<const float4*>(brow + k0);
            const float4 x1 = *reinterpret_cast<const float4*>(brow + k0 + 4);
            Bs[kA + 0][mA] = x0.x; Bs[kA + 1][mA] = x0.y;
            Bs[kA + 2][mA] = x0.z; Bs[kA + 3][mA] = x0.w;
            Bs[kA + 4][mA] = x1.x; Bs[kA + 5][mA] = x1.y;
            Bs[kA + 6][mA] = x1.z; Bs[kA + 7][mA] = x1.w;
        }
        __syncthreads();
#pragma unroll 4
        for (int k = 0; k < 16; k++) {
            float a[8], b[8];
            *reinterpret_cast<float4*>(&a[0]) = *reinterpret_cast<const float4*>(&As[k][ty << 2]);
            *reinterpret_cast<float4*>(&a[4]) = *reinterpret_cast<const float4*>(&As[k][64 + (ty << 2)]);
            *reinterpret_cast<float4*>(&b[0]) = *reinterpret_cast<const float4*>(&Bs[k][tx << 2]);
            *reinterpret_cast<float4*>(&b[4]) = *reinterpret_cast<const float4*>(&Bs[k][64 + (tx << 2)]);
#pragma unroll
            for (int r = 0; r < 8; r++)
#pragma unroll
                for (int c = 0; c < 8; c++) acc[r][c] += a[r] * b[c];
        }
        __syncthreads();
    }

#pragma unroll
    for (int rh = 0; rh < 2; rh++) {
#pragma unroll
        for (int r = 0; r < 4; r++) {
            const int ri = (rh << 2) + r;
            const int row = m0 + rh * 64 + (ty << 2) + r;
#pragma unroll
            for (int ch = 0; ch < 2; ch++) {
                float4 v4;
#pragma unroll
                for (int c = 0; c < 4; c++) (&v4.x)[c] = acc[ri][(ch << 2) + c];
                if (x < 6) {
                    const int col = x * 128 + ch * 64 + (tx << 2);
                    *reinterpret_cast<float4*>(&q[(size_t)row * HH + col]) = v4;
                } else {
                    float* dst = (ch == 0) ? kf : vf;
                    *reinterpret_cast<float4*>(&dst[(size_t)row * HDIM + (tx << 2)]) = v4;
                }
            }
        }
    }
}

// ---------------- fp32 flash-tile attention v3: stride-64 XOR-swizzled LDS, true b128 ----
// slot4(r,c4) = c4 ^ ((r>>2)&7): bijective per row; all accesses 16B-aligned.
#define SW4(r, c4) ((((c4) ^ (((r) >> 2) & 7))) << 2)
__global__ __launch_bounds__(256) void k_fattn(const float* __restrict__ q,
                                               const float* __restrict__ kf,
                                               const float* __restrict__ vf,
                                               const float* __restrict__ mask,
                                               float* __restrict__ out) {
    __shared__ __align__(16) float Qs[64][64];
    __shared__ __align__(16) float Ks[64][64];
    __shared__ __align__(16) float Vs[64][64];
    __shared__ __align__(16) float Ps[64][64];

    const int blk = blockIdx.x;
    const int qt = blk & 31;
    const int bh = blk >> 5;
    const int nh = bh % NHEAD;
    const int b  = bh / NHEAD;
    const int q0 = qt * 64;

    const int tid = threadIdx.x;
    const int ty = tid >> 4;
    const int tx = tid & 15;
    const int sr = tid >> 2;            // staging row 0..63
    const int sc4 = (tid & 3) << 2;     // staging col4 group base 0,4,8,12

    // stage Q (pre-scaled by exact pow2 0.125)
    {
        const float* src = q + (size_t)(b * SEQ + q0 + sr) * HH + nh * HDIM + (sc4 << 2);
#pragma unroll
        for (int i = 0; i < 4; i++) {
            float4 v4 = *reinterpret_cast<const float4*>(src + i * 4);
            v4.x *= 0.125f; v4.y *= 0.125f; v4.z *= 0.125f; v4.w *= 0.125f;
            *reinterpret_cast<float4*>(&Qs[sr][SW4(sr, sc4 + i)]) = v4;
        }
    }

    const float* kb = kf + (size_t)b * SEQ * HDIM;
    const float* vb = vf + (size_t)b * SEQ * HDIM;
    const float* mb = mask + b * SEQ;

    float m[4], l[4], o[4][4];
#pragma unroll
    for (int r = 0; r < 4; r++) {
        m[r] = -3.4028234663852886e38f; l[r] = 0.f;
#pragma unroll
        for (int c = 0; c < 4; c++) o[r][c] = 0.f;
    }

    // prefetch K/V tile 0 into registers
    float4 kr[4], vr[4];
    {
        const float* ksrc = kb + (size_t)sr * HDIM + (sc4 << 2);
        const float* vsrc = vb + (size_t)sr * HDIM + (sc4 << 2);
#pragma unroll
        for (int i = 0; i < 4; i++) {
            kr[i] = *reinterpret_cast<const float4*>(ksrc + i * 4);
            vr[i] = *reinterpret_cast<const float4*>(vsrc + i * 4);
        }
    }

    for (int k0 = 0; k0 < SEQ; k0 += 64) {
        __syncthreads();   // B1: prev PV done reading Ps/Vs
        // write prefetched K/V regs -> LDS (swizzled, conflict-free)
#pragma unroll
        for (int i = 0; i < 4; i++) {
            *reinterpret_cast<float4*>(&Ks[sr][SW4(sr, sc4 + i)]) = kr[i];
            *reinterpret_cast<float4*>(&Vs[sr][SW4(sr, sc4 + i)]) = vr[i];
        }
        // issue prefetch for next tile (lands during this tile's compute)
        if (k0 + 64 < SEQ) {
            const float* ksrc = kb + (size_t)(k0 + 64 + sr) * HDIM + (sc4 << 2);
            const float* vsrc = vb + (size_t)(k0 + 64 + sr) * HDIM + (sc4 << 2);
#pragma unroll
            for (int i = 0; i < 4; i++) {
                kr[i] = *reinterpret_cast<const float4*>(ksrc + i * 4);
                vr[i] = *reinterpret_cast<const float4*>(vsrc + i * 4);
            }
        }
        __syncthreads();   // B2: Ks/Vs (and Qs on first iter) ready

        // S = Q K^T
        float s[4][4];
#pragma unroll
        for (int r = 0; r < 4; r++)
#pragma unroll
            for (int c = 0; c < 4; c++) s[r][c] = 0.f;
#pragma unroll 4
        for (int d4 = 0; d4 < 16; d4++) {
            float4 a4[4], b4[4];
#pragma unroll
            for (int r = 0; r < 4; r++) {
                const int row = (ty << 2) + r;
                a4[r] = *reinterpret_cast<const float4*>(&Qs[row][SW4(row, d4)]);
            }
#pragma unroll
            for (int c = 0; c < 4; c++) {
                const int row = (tx << 2) + c;
                b4[c] = *reinterpret_cast<const float4*>(&Ks[row][SW4(row, d4)]);
            }
#pragma unroll
            for (int r = 0; r < 4; r++)
#pragma unroll
                for (int c = 0; c < 4; c++)
                    s[r][c] += a4[r].x * b4[c].x + a4[r].y * b4[c].y + a4[r].z * b4[c].z + a4[r].w * b4[c].w;
        }
#pragma unroll
        for (int c = 0; c < 4; c++) {
            const float madd = (1.f - mb[k0 + (tx << 2) + c]) * -3.4028234663852886e38f;
#pragma unroll
            for (int r = 0; r < 4; r++) s[r][c] += madd;
        }
        float tm[4];
#pragma unroll
        for (int r = 0; r < 4; r++) tm[r] = fmaxf(fmaxf(s[r][0], s[r][1]), fmaxf(s[r][2], s[r][3]));
#pragma unroll
        for (int off = 8; off; off >>= 1)
#pragma unroll
            for (int r = 0; r < 4; r++) tm[r] = fmaxf(tm[r], __shfl_xor(tm[r], off));
        float alpha[4], rs[4];
#pragma unroll
        for (int r = 0; r < 4; r++) {
            const float mn = fmaxf(m[r], tm[r]);
            alpha[r] = __expf(m[r] - mn);
            m[r] = mn;
            const float p0 = __expf(s[r][0] - mn);
            const float p1 = __expf(s[r][1] - mn);
            const float p2 = __expf(s[r][2] - mn);
            const float p3 = __expf(s[r][3] - mn);
            s[r][0] = p0; s[r][1] = p1; s[r][2] = p2; s[r][3] = p3;
            rs[r] = (p0 + p1) + (p2 + p3);
        }
#pragma unroll
        for (int off = 8; off; off >>= 1)
#pragma unroll
            for (int r = 0; r < 4; r++) rs[r] += __shfl_xor(rs[r], off);
#pragma unroll
        for (int r = 0; r < 4; r++) l[r] = l[r] * alpha[r] + rs[r];

        // P write to its own buffer (no barrier needed before: nothing reads Ps now)
#pragma unroll
        for (int r = 0; r < 4; r++) {
            const int row = (ty << 2) + r;
            *reinterpret_cast<float4*>(&Ps[row][SW4(row, tx)]) =
                make_float4(s[r][0], s[r][1], s[r][2], s[r][3]);
        }
        __syncthreads();   // B3: Ps ready

#pragma unroll
        for (int r = 0; r < 4; r++)
#pragma unroll
            for (int c = 0; c < 4; c++) o[r][c] *= alpha[r];
#pragma unroll 4
        for (int kk4 = 0; kk4 < 16; kk4++) {
            float4 p4[4], v40, v41, v42, v43;
#pragma unroll
            for (int r = 0; r < 4; r++) {
                const int row = (ty << 2) + r;
                p4[r] = *reinterpret_cast<const float4*>(&Ps[row][SW4(row, kk4)]);
            }
            const int kk0 = kk4 << 2;
            v40 = *reinterpret_cast<const float4*>(&Vs[kk0 + 0][SW4(kk0 + 0, tx)]);
            v41 = *reinterpret_cast<const float4*>(&Vs[kk0 + 1][SW4(kk0 + 1, tx)]);
            v42 = *reinterpret_cast<const float4*>(&Vs[kk0 + 2][SW4(kk0 + 2, tx)]);
            v43 = *reinterpret_cast<const float4*>(&Vs[kk0 + 3][SW4(kk0 + 3, tx)]);
#pragma unroll
            for (int r = 0; r < 4; r++) {
                o[r][0] += p4[r].x * v40.x + p4[r].y * v41.x + p4[r].z * v42.x + p4[r].w * v43.x;
                o[r][1] += p4[r].x * v40.y + p4[r].y * v41.y + p4[r].z * v42.y + p4[r].w * v43.y;
                o[r][2] += p4[r].x * v40.z + p4[r].y * v41.z + p4[r].z * v42.z + p4[r].w * v43.z;
                o[r][3] += p4[r].x * v40.w + p4[r].y * v41.w + p4[r].z * v42.w + p4[r].w * v43.w;
            }
        }
    }

#pragma unroll
    for (int r = 0; r < 4; r++) {
        const float invl = 1.f / l[r];
        const int tq = b * SEQ + q0 + (ty << 2) + r;
        float* dst = out + (size_t)tq * HH + nh * HDIM + (tx << 2);
        *reinterpret_cast<float4*>(dst) =
            make_float4(o[r][0] * invl, o[r][1] * invl, o[r][2] * invl, o[r][3] * invl);
    }
}
#undef SW4

// ---------------- gating: fp32 logits + softmax over 8 experts ----------------
__global__ __launch_bounds__(64) void k_gate(const float* __restrict__ x, const float* __restrict__ gw,
                                             float* __restrict__ scoresT) {
    const int t = blockIdx.x;
    const int lane = threadIdx.x;
    const float* row = x + (size_t)t * HH;
    float acc[8];
#pragma unroll
    for (int e = 0; e < 8; e++) acc[e] = 0.f;
    for (int d = lane; d < HH; d += 64) {
        const float xv = row[d];
#pragma unroll
        for (int e = 0; e < 8; e++) acc[e] += xv * gw[e * HH + d];
    }
#pragma unroll
    for (int e = 0; e < 8; e++) {
#pragma unroll
        for (int off = 32; off; off >>= 1) acc[e] += __shfl_xor(acc[e], off);
    }
    if (lane == 0) {
        float mx = acc[0];
#pragma unroll
        for (int e = 1; e < 8; e++) mx = fmaxf(mx, acc[e]);
        float ex[8], ssum = 0.f;
#pragma unroll
        for (int e = 0; e < 8; e++) { ex[e] = __expf(acc[e] - mx); ssum += ex[e]; }
        const float inv = 1.f / ssum;
#pragma unroll
        for (int e = 0; e < 8; e++) scoresT[(size_t)e * TT + t] = ex[e] * inv;
    }
}

// ---------------- per-expert exact top-640 via bitonic sort (jax tie-break) ----------------
__global__ __launch_bounds__(1024) void k_topk(const float* __restrict__ scoresT,
                                               int* __restrict__ top_i, float* __restrict__ top_s) {
    __shared__ unsigned long long keys[4096];
    const int e = blockIdx.x;
    const int tid = threadIdx.x;
    for (int i = tid; i < 4096; i += 1024) {
        const float sv = scoresT[(size_t)e * TT + i];
        keys[i] = (((unsigned long long)__float_as_uint(sv)) << 32) |
                  (unsigned long long)(0xFFFFFFFFu - (unsigned)i);
    }
    __syncthreads();
    for (int k = 2; k <= 4096; k <<= 1) {
        for (int j = k >> 1; j > 0; j >>= 1) {
            for (int i = tid; i < 4096; i += 1024) {
                const int ixj = i ^ j;
                if (ixj > i) {
                    const bool up = ((i & k) == 0);
                    const unsigned long long a = keys[i], bb = keys[ixj];
                    if ((a > bb) == up) { keys[i] = bb; keys[ixj] = a; }
                }
            }
            __syncthreads();
        }
    }
    for (int c = tid; c < CAP; c += 1024) {
        const unsigned long long u = keys[4095 - c];
        top_i[e * CAP + c] = (int)(0xFFFFFFFFu - (unsigned)(u & 0xFFFFFFFFull));
        top_s[e * CAP + c] = __uint_as_float((unsigned)(u >> 32));
    }
}

// ---------------- explicit gather / scatter for MoE (fp32) ----------------
__global__ __launch_bounds__(192) void k_gather(const int* __restrict__ top_i, const float* __restrict__ hn,
                                                float* __restrict__ xg) {
    const int ec = blockIdx.x;
    const int tok = top_i[ec];
    const float4 v = *reinterpret_cast<const float4*>(hn + (size_t)tok * HH + threadIdx.x * 4);
    *reinterpret_cast<float4*>(xg + (size_t)ec * HH + threadIdx.x * 4) = v;
}

__global__ __launch_bounds__(192) void k_scatter(const int* __restrict__ top_i, const float* __restrict__ top_s,
                                                 const float* __restrict__ oute, float* __restrict__ h) {
    const int ec = blockIdx.x;
    const int tok = top_i[ec];
    const float sc = top_s[ec];
    const float4 v = *reinterpret_cast<const float4*>(oute + (size_t)ec * HH + threadIdx.x * 4);
    float* dst = h + (size_t)tok * HH + threadIdx.x * 4;
    atomicAdd(dst + 0, v.x * sc);
    atomicAdd(dst + 1, v.y * sc);
    atomicAdd(dst + 2, v.z * sc);
    atomicAdd(dst + 3, v.w * sc);
}

__global__ __launch_bounds__(512) void k_lb(const float* __restrict__ top_s, float* __restrict__ lb_out) {
    __shared__ float sums[8];
    const int w = threadIdx.x >> 6, lane = threadIdx.x & 63;
    float s = 0.f;
    for (int c = lane; c < CAP; c += 64) s += top_s[w * CAP + c];
#pragma unroll
    for (int off = 32; off; off >>= 1) s += __shfl_xor(s, off);
    if (lane == 0) sums[w] = s;
    __syncthreads();
    if (threadIdx.x == 0) {
        float mean = 0.f, load[8];
#pragma unroll
        for (int e2 = 0; e2 < 8; e2++) { load[e2] = sums[e2] * (1.f / 4096.f); mean += load[e2]; }
        mean *= 0.125f;
        float var = 0.f;
#pragma unroll
        for (int e2 = 0; e2 < 8; e2++) { const float d = load[e2] - mean; var += d * d; }
        lb_out[0] = var * (1.f / 7.f) * 8.f;
    }
}

__global__ void k_fin(const float* __restrict__ lb, float* __restrict__ dst) {
    if (threadIdx.x == 0 && blockIdx.x == 0) dst[0] = lb[0] + lb[1];
}

extern "C" void kernel_launch(void* const* d_in, const int* in_sizes, int n_in,
                              void* d_out, int out_size, void* d_ws, size_t ws_size,
                              hipStream_t stream)
{
    const int*   ids_raw = (const int*)d_in[0];
    const float* mask  = (const float*)d_in[1];
    const float* embw  = (const float*)d_in[2];
    const float* ln1g  = (const float*)d_in[3];
    const float* ln1b  = (const float*)d_in[4];
    const float* qw    = (const float*)d_in[5];
    const float* kw    = (const float*)d_in[6];
    const float* vw    = (const float*)d_in[7];
    const float* ow    = (const float*)d_in[8];
    const float* ln2g  = (const float*)d_in[9];
    const float* ln2b  = (const float*)d_in[10];
    const float* gw    = (const float*)d_in[11];
    const float* w1    = (const float*)d_in[12];
    const float* b1    = (const float*)d_in[13];
    const float* w2    = (const float*)d_in[14];
    const float* b2    = (const float*)d_in[15];
    const float* lnfg  = (const float*)d_in[16];
    const float* lnfb  = (const float*)d_in[17];
    const float* headw = (const float*)d_in[18];
    float* out = (float*)d_out;

    char* wsb = (char*)d_ws;
    size_t off = 0;
    auto alloc = [&](size_t bytes) -> void* {
        off = (off + 255) & ~(size_t)255;
        void* p = wsb + off;
        off += bytes;
        return p;
    };
    float* h0  = (float*)alloc((size_t)TT * HH * 4);
    float* h1b = (float*)alloc((size_t)TT * HH * 4);
    float* hn  = (float*)alloc((size_t)TT * HH * 4);
    float* q   = (float*)alloc((size_t)TT * HH * 4);
    float* kf  = (float*)alloc((size_t)TT * HDIM * 4);
    float* vf  = (float*)alloc((size_t)TT * HDIM * 4);
    float* scoresT = (float*)alloc((size_t)NEXP * TT * 4);
    int*   idsn    = (int*)alloc((size_t)TT * 4);
    int*   top_i   = (int*)alloc((size_t)NEXP * CAP * 4);
    float* top_s   = (float*)alloc((size_t)NEXP * CAP * 4);
    float* lb      = (float*)alloc(64);
    if (off > ws_size) return;

    // optional bf16 head buffers (ws-gated; bit-identical results either path)
    unsigned short* hnb = (unsigned short*)alloc((size_t)TT * HH * 2);
    unsigned short* hwb = (unsigned short*)alloc((size_t)VOCAB * HH * 2);
    const bool bighead = (off <= ws_size);

    char* outb = (char*)d_out;
    size_t ooff = 0;
    auto oalloc = [&](size_t bytes) -> void* {
        ooff = (ooff + 255) & ~(size_t)255;
        void* p = outb + ooff;
        ooff += bytes;
        return p;
    };
    float* xg   = (float*)oalloc((size_t)NEXP * CAP * HH * 4);
    float* act  = (float*)oalloc((size_t)NEXP * CAP * FDIM * 4);
    float* oute = (float*)oalloc((size_t)NEXP * CAP * HH * 4);

    k_ids<<<16, 256, 0, stream>>>(ids_raw, idsn);
    k_embed<<<TT, 192, 0, stream>>>(idsn, embw, h0);

    float* hc = h0;
    float* ho = h1b;
    for (int l = 0; l < 2; l++) {
        k_ln<<<TT, 64, 0, stream>>>(hc, ln1g + l * HH, ln1b + l * HH, hn);
        k_qkv<<<dim3(7, TT/128), 256, 0, stream>>>(
            hn, qw + (size_t)l * HH * HH, kw + (size_t)l * HDIM * HH, vw + (size_t)l * HDIM * HH,
            q, kf, vf);
        k_fattn<<<2 * NHEAD * (SEQ / 64), 256, 0, stream>>>(q, kf, vf, mask, hn);
        k_sgemm128<true,false,false,true>
            <<<dim3(TT/128, HH/128, 1), 256, 0, stream>>>(
            hn, ow + (size_t)l * HH * HH, nullptr, hc, ho, TT, HH, HH, 0, 0, 0, 0);
        k_ln<<<TT, 64, 0, stream>>>(ho, ln2g + l * HH, ln2b + l * HH, hn);
        k_gate<<<TT, 64, 0, stream>>>(hn, gw + (size_t)l * NEXP * HH, scoresT);
        k_topk<<<NEXP, 1024, 0, stream>>>(scoresT, top_i, top_s);
        k_gather<<<NEXP * CAP, 192, 0, stream>>>(top_i, hn, xg);
        if (l == 1) {
            k_gemm<false,false,true,true,false,float,float>
                <<<dim3(FDIM/64, CAP/64, NEXP), 256, 0, stream>>>(
                xg, w1 + (size_t)l * NEXP * HH * FDIM, b1 + (size_t)l * NEXP * FDIM, nullptr, act,
                CAP, FDIM, HH, (long long)CAP * HH, (long long)HH * FDIM, FDIM, (long long)CAP * FDIM);
            k_gemm<false,false,true,false,false,float,float>
                <<<dim3(HH/64, CAP/64, NEXP), 256, 0, stream>>>(
                act, w2 + (size_t)l * NEXP * FDIM * HH, b2 + (size_t)l * NEXP * HH, nullptr, oute,
                CAP, HH, FDIM, (long long)CAP * FDIM, (long long)FDIM * HH, HH, (long long)CAP * HH);
        } else {
            k_sgemm128<false,true,true,false>
                <<<dim3(CAP/128, FDIM/128, NEXP), 256, 0, stream>>>(
                xg, w1 + (size_t)l * NEXP * HH * FDIM, b1 + (size_t)l * NEXP * FDIM, nullptr, act,
                CAP, FDIM, HH, (long long)CAP * HH, (long long)HH * FDIM, FDIM, (long long)CAP * FDIM);
            k_sgemm128<false,true,false,false>
                <<<dim3(CAP/128, HH/128, NEXP), 256, 0, stream>>>(
                act, w2 + (size_t)l * NEXP * FDIM * HH, b2 + (size_t)l * NEXP * HH, nullptr, oute,
                CAP, HH, FDIM, (long long)CAP * FDIM, (long long)FDIM * HH, HH, (long long)CAP * HH);
        }
        k_scatter<<<NEXP * CAP, 192, 0, stream>>>(top_i, top_s, oute, ho);
        k_lb<<<1, 512, 0, stream>>>(top_s, lb + l);
        float* tmp = hc; hc = ho; ho = tmp;
    }
    k_ln<<<TT, 64, 0, stream>>>(hc, lnfg, lnfb, hn);
    if (bighead) {
        k_tobf<<<(TT * HH / 8 + 255) / 256, 256, 0, stream>>>(hn, hnb, TT * HH / 8);
        k_tobf<<<(VOCAB * HH / 8 + 255) / 256, 256, 0, stream>>>(headw, hwb, VOCAB * HH / 8);
        k_gemm128b<<<dim3(TT/128, VOCAB/128, 1), 256, 0, stream>>>(hnb, hwb, out, TT, VOCAB, HH);
    } else {
        k_gemm128<<<dim3(TT/128, VOCAB/128, 1), 256, 0, stream>>>(hn, headw, out, TT, VOCAB, HH);
    }
    k_fin<<<1, 64, 0, stream>>>(lb, out + (size_t)TT * VOCAB);
}

// Round 11
// 2776.311 us; speedup vs baseline: 1.2131x; 1.2131x over previous
//
#include <hip/hip_runtime.h>
#include <math.h>

#define TT 4096
#define HH 768
#define NHEAD 12
#define HDIM 64
#define NEXP 8
#define FDIM 1536
#define CAP 640
#define SEQ 2048
#define VOCAB 32000

typedef __attribute__((ext_vector_type(4))) float f32x4;
typedef __attribute__((ext_vector_type(8))) short bf16x8;

__device__ __forceinline__ unsigned short f2bf(float f) {
    unsigned int u = __float_as_uint(f);
    unsigned int r = u + 0x7fffu + ((u >> 16) & 1u);
    return (unsigned short)(r >> 16);
}

// --------- input_ids normalize (robust to int32 or int64 host layout) ---------
__global__ __launch_bounds__(256) void k_ids(const int* __restrict__ in, int* __restrict__ outi) {
    __shared__ int is64;
    if (threadIdx.x == 0) {
        int o = 0;
        for (int i = 1; i < 128; i += 2) o |= in[i];
        is64 = (o == 0) ? 1 : 0;
    }
    __syncthreads();
    const int stride = is64 ? 2 : 1;
    for (int t = threadIdx.x + blockIdx.x * 256; t < TT; t += gridDim.x * 256) {
        int v = in[t * stride];
        v = v < 0 ? 0 : (v >= VOCAB ? VOCAB - 1 : v);
        outi[t] = v;
    }
}

__global__ __launch_bounds__(192) void k_embed(const int* __restrict__ ids, const float* __restrict__ ew,
                                               float* __restrict__ h) {
    const int t = blockIdx.x;
    const int id = ids[t];
    const float4* src = reinterpret_cast<const float4*>(ew + (size_t)id * HH);
    float4* dst = reinterpret_cast<float4*>(h + (size_t)t * HH);
    dst[threadIdx.x] = src[threadIdx.x];
}

__global__ __launch_bounds__(64) void k_ln(const float* __restrict__ x, const float* __restrict__ g,
                                           const float* __restrict__ b, float* __restrict__ y) {
    const int t = blockIdx.x;
    const int lane = threadIdx.x;
    const float* row = x + (size_t)t * HH;
    float v[12];
    float s = 0.f, sq = 0.f;
#pragma unroll
    for (int i = 0; i < 12; i++) {
        float f = row[lane + (i << 6)];
        v[i] = f; s += f; sq += f * f;
    }
#pragma unroll
    for (int off = 32; off; off >>= 1) { s += __shfl_xor(s, off); sq += __shfl_xor(sq, off); }
    const float mean = s * (1.f / 768.f);
    float var = sq * (1.f / 768.f) - mean * mean;
    var = fmaxf(var, 0.f);
    const float rstd = rsqrtf(var + 1e-5f);
    float* yr = y + (size_t)t * HH;
#pragma unroll
    for (int i = 0; i < 12; i++) {
        const int d = lane + (i << 6);
        yr[d] = (v[i] - mean) * rstd * g[d] + b[d];
    }
}

// ---------------- fp32 -> bf16 convert (8 elems/thread) ----------------
__global__ __launch_bounds__(256) void k_tobf(const float* __restrict__ in, unsigned short* __restrict__ outb,
                                              const int n8) {
    const int i = blockIdx.x * 256 + threadIdx.x;
    if (i >= n8) return;
    const float4 x0 = *reinterpret_cast<const float4*>(in + (size_t)i * 8);
    const float4 x1 = *reinterpret_cast<const float4*>(in + (size_t)i * 8 + 4);
    ushort4 o0, o1;
    o0.x = f2bf(x0.x); o0.y = f2bf(x0.y); o0.z = f2bf(x0.z); o0.w = f2bf(x0.w);
    o1.x = f2bf(x1.x); o1.y = f2bf(x1.y); o1.z = f2bf(x1.z); o1.w = f2bf(x1.w);
    *reinterpret_cast<ushort4*>(outb + (size_t)i * 8) = o0;
    *reinterpret_cast<ushort4*>(outb + (size_t)i * 8 + 4) = o1;
}

// ---------------- bf16-MFMA GEMM 64x64 (proven): C = A(MxK) * B ----------------
template<bool BT, bool XMAJ, bool BIAS, bool GELU, bool RESID, typename AT, typename OT>
__global__ __launch_bounds__(256) void k_gemm(
    const AT* __restrict__ A, const float* __restrict__ B,
    const float* __restrict__ bias, const float* __restrict__ resid,
    OT* __restrict__ C,
    const int M, const int N, const int K,
    const long long eA, const long long eB, const long long eBias, const long long eC)
{
    const int e = blockIdx.z;
    A += e * eA; B += e * eB; C += e * eC;
    if (BIAS) bias += e * eBias;

    __shared__ __align__(16) short As[64][40];
    __shared__ __align__(16) short Bs[64][40];

    const int tid = threadIdx.x;
    const int lane = tid & 63;
    const int w = tid >> 6;
    const int n0 = (XMAJ ? blockIdx.y : blockIdx.x) * 64;
    const int m0 = (XMAJ ? blockIdx.x : blockIdx.y) * 64;

    f32x4 zero = {0.f, 0.f, 0.f, 0.f};
    f32x4 acc[4];
#pragma unroll
    for (int c = 0; c < 4; c++) acc[c] = zero;

    const int ar = tid >> 2;
    const int ak = (tid & 3) << 3;
    const AT* aptr = A + (size_t)(m0 + ar) * K + ak;

    for (int k0 = 0; k0 < K; k0 += 32) {
        if constexpr (sizeof(AT) == 4) {
            const float* ap = reinterpret_cast<const float*>(aptr) + k0;
            const float4 x0 = *reinterpret_cast<const float4*>(ap);
            const float4 x1 = *reinterpret_cast<const float4*>(ap + 4);
            short* d = &As[ar][ak];
            d[0] = (short)f2bf(x0.x); d[1] = (short)f2bf(x0.y);
            d[2] = (short)f2bf(x0.z); d[3] = (short)f2bf(x0.w);
            d[4] = (short)f2bf(x1.x); d[5] = (short)f2bf(x1.y);
            d[6] = (short)f2bf(x1.z); d[7] = (short)f2bf(x1.w);
        } else {
            const unsigned short* ap = reinterpret_cast<const unsigned short*>(aptr) + k0;
            *reinterpret_cast<int4*>(&As[ar][ak]) = *reinterpret_cast<const int4*>(ap);
        }
        if constexpr (BT) {
            const float* bp = B + (size_t)(n0 + ar) * K + k0 + ak;
            const float4 x0 = *reinterpret_cast<const float4*>(bp);
            const float4 x1 = *reinterpret_cast<const float4*>(bp + 4);
            short* d = &Bs[ar][ak];
            d[0] = (short)f2bf(x0.x); d[1] = (short)f2bf(x0.y);
            d[2] = (short)f2bf(x0.z); d[3] = (short)f2bf(x0.w);
            d[4] = (short)f2bf(x1.x); d[5] = (short)f2bf(x1.y);
            d[6] = (short)f2bf(x1.z); d[7] = (short)f2bf(x1.w);
        } else {
            const int kk = tid >> 6;
            const int nn = tid & 63;
#pragma unroll
            for (int it = 0; it < 8; it++) {
                const int kl = kk + (it << 2);
                Bs[nn][kl] = (short)f2bf(B[(size_t)(k0 + kl) * N + n0 + nn]);
            }
        }
        __syncthreads();
        const bf16x8 af = *reinterpret_cast<const bf16x8*>(&As[(w << 4) + (lane & 15)][(lane >> 4) << 3]);
#pragma unroll
        for (int c = 0; c < 4; c++) {
            const bf16x8 bfr = *reinterpret_cast<const bf16x8*>(&Bs[(c << 4) + (lane & 15)][(lane >> 4) << 3]);
            acc[c] = __builtin_amdgcn_mfma_f32_16x16x32_bf16(af, bfr, acc[c], 0, 0, 0);
        }
        __syncthreads();
    }

    const int rb = (w << 4) + ((lane >> 4) << 2);
    const int cl = lane & 15;
#pragma unroll
    for (int c = 0; c < 4; c++) {
        const int col = n0 + (c << 4) + cl;
        float bv = 0.f;
        if constexpr (BIAS) bv = bias[col];
#pragma unroll
        for (int r = 0; r < 4; r++) {
            const int lrow = m0 + rb + r;
            float v = acc[c][r] + bv;
            if constexpr (GELU) v = 0.5f * v * (1.f + erff(v * 0.70710678118654752f));
            if constexpr (RESID) v += resid[(size_t)lrow * N + col];
            if constexpr (sizeof(OT) == 2) {
                C[(size_t)lrow * N + col] = (OT)f2bf(v);
            } else {
                C[(size_t)lrow * N + col] = v;
            }
        }
    }
}

// ---------------- bf16-MFMA GEMM 128x128 fp32-in (head fallback): C = A*B^T ----------------
__global__ __launch_bounds__(256) void k_gemm128(
    const float* __restrict__ A, const float* __restrict__ B, float* __restrict__ C,
    const int M, const int N, const int K)
{
    __shared__ __align__(16) short As[128][40];
    __shared__ __align__(16) short Bs[128][40];

    const int tid = threadIdx.x;
    const int lane = tid & 63;
    const int w = tid >> 6;
    const int wm = w >> 1, wn = w & 1;
    const int m0 = blockIdx.x * 128, n0 = blockIdx.y * 128;

    f32x4 zero = {0.f, 0.f, 0.f, 0.f};
    f32x4 acc[4][4];
#pragma unroll
    for (int mi = 0; mi < 4; mi++)
#pragma unroll
        for (int ni = 0; ni < 4; ni++) acc[mi][ni] = zero;

    const int srow = tid >> 1;
    const int sk = (tid & 1) << 4;
    const float* aptr = A + (size_t)(m0 + srow) * K + sk;
    const float* bptr = B + (size_t)(n0 + srow) * K + sk;

    const int kh = (lane >> 4) << 3;
    const int l15 = lane & 15;

    for (int k0 = 0; k0 < K; k0 += 32) {
        {
            const float4 a0 = *reinterpret_cast<const float4*>(aptr + k0);
            const float4 a1 = *reinterpret_cast<const float4*>(aptr + k0 + 4);
            const float4 a2 = *reinterpret_cast<const float4*>(aptr + k0 + 8);
            const float4 a3 = *reinterpret_cast<const float4*>(aptr + k0 + 12);
            short* d = &As[srow][sk];
            d[0]  = (short)f2bf(a0.x); d[1]  = (short)f2bf(a0.y);
            d[2]  = (short)f2bf(a0.z); d[3]  = (short)f2bf(a0.w);
            d[4]  = (short)f2bf(a1.x); d[5]  = (short)f2bf(a1.y);
            d[6]  = (short)f2bf(a1.z); d[7]  = (short)f2bf(a1.w);
            d[8]  = (short)f2bf(a2.x); d[9]  = (short)f2bf(a2.y);
            d[10] = (short)f2bf(a2.z); d[11] = (short)f2bf(a2.w);
            d[12] = (short)f2bf(a3.x); d[13] = (short)f2bf(a3.y);
            d[14] = (short)f2bf(a3.z); d[15] = (short)f2bf(a3.w);
            const float4 b0 = *reinterpret_cast<const float4*>(bptr + k0);
            const float4 b1 = *reinterpret_cast<const float4*>(bptr + k0 + 4);
            const float4 b2 = *reinterpret_cast<const float4*>(bptr + k0 + 8);
            const float4 b3 = *reinterpret_cast<const float4*>(bptr + k0 + 12);
            short* e = &Bs[srow][sk];
            e[0]  = (short)f2bf(b0.x); e[1]  = (short)f2bf(b0.y);
            e[2]  = (short)f2bf(b0.z); e[3]  = (short)f2bf(b0.w);
            e[4]  = (short)f2bf(b1.x); e[5]  = (short)f2bf(b1.y);
            e[6]  = (short)f2bf(b1.z); e[7]  = (short)f2bf(b1.w);
            e[8]  = (short)f2bf(b2.x); e[9]  = (short)f2bf(b2.y);
            e[10] = (short)f2bf(b2.z); e[11] = (short)f2bf(b2.w);
            e[12] = (short)f2bf(b3.x); e[13] = (short)f2bf(b3.y);
            e[14] = (short)f2bf(b3.z); e[15] = (short)f2bf(b3.w);
        }
        __syncthreads();
        bf16x8 af[4], bfr[4];
#pragma unroll
        for (int mi = 0; mi < 4; mi++)
            af[mi] = *reinterpret_cast<const bf16x8*>(&As[wm * 64 + mi * 16 + l15][kh]);
#pragma unroll
        for (int ni = 0; ni < 4; ni++)
            bfr[ni] = *reinterpret_cast<const bf16x8*>(&Bs[wn * 64 + ni * 16 + l15][kh]);
#pragma unroll
        for (int mi = 0; mi < 4; mi++)
#pragma unroll
            for (int ni = 0; ni < 4; ni++)
                acc[mi][ni] = __builtin_amdgcn_mfma_f32_16x16x32_bf16(af[mi], bfr[ni], acc[mi][ni], 0, 0, 0);
        __syncthreads();
    }

    const int rb = (lane >> 4) << 2;
    const int cl = lane & 15;
#pragma unroll
    for (int mi = 0; mi < 4; mi++) {
#pragma unroll
        for (int ni = 0; ni < 4; ni++) {
            const int col = n0 + wn * 64 + ni * 16 + cl;
#pragma unroll
            for (int r = 0; r < 4; r++) {
                const int row = m0 + wm * 64 + mi * 16 + rb + r;
                C[(size_t)row * N + col] = acc[mi][ni][r];
            }
        }
    }
}

// ---------------- bf16-MFMA GEMM 128x128, pre-converted bf16 inputs (head fast path) -------
__global__ __launch_bounds__(256) void k_gemm128b(
    const unsigned short* __restrict__ A, const unsigned short* __restrict__ B, float* __restrict__ C,
    const int M, const int N, const int K)
{
    __shared__ __align__(16) short As[128][40];
    __shared__ __align__(16) short Bs[128][40];

    const int tid = threadIdx.x;
    const int lane = tid & 63;
    const int w = tid >> 6;
    const int wm = w >> 1, wn = w & 1;
    const int m0 = blockIdx.x * 128, n0 = blockIdx.y * 128;

    f32x4 zero = {0.f, 0.f, 0.f, 0.f};
    f32x4 acc[4][4];
#pragma unroll
    for (int mi = 0; mi < 4; mi++)
#pragma unroll
        for (int ni = 0; ni < 4; ni++) acc[mi][ni] = zero;

    const int srow = tid >> 1;
    const int sk = (tid & 1) << 4;
    const unsigned short* aptr = A + (size_t)(m0 + srow) * K + sk;
    const unsigned short* bptr = B + (size_t)(n0 + srow) * K + sk;

    const int kh = (lane >> 4) << 3;
    const int l15 = lane & 15;

    for (int k0 = 0; k0 < K; k0 += 32) {
        {
            const int4* a4 = reinterpret_cast<const int4*>(aptr + k0);
            *reinterpret_cast<int4*>(&As[srow][sk]) = a4[0];
            *reinterpret_cast<int4*>(&As[srow][sk + 8]) = a4[1];
            const int4* b4 = reinterpret_cast<const int4*>(bptr + k0);
            *reinterpret_cast<int4*>(&Bs[srow][sk]) = b4[0];
            *reinterpret_cast<int4*>(&Bs[srow][sk + 8]) = b4[1];
        }
        __syncthreads();
        bf16x8 af[4], bfr[4];
#pragma unroll
        for (int mi = 0; mi < 4; mi++)
            af[mi] = *reinterpret_cast<const bf16x8*>(&As[wm * 64 + mi * 16 + l15][kh]);
#pragma unroll
        for (int ni = 0; ni < 4; ni++)
            bfr[ni] = *reinterpret_cast<const bf16x8*>(&Bs[wn * 64 + ni * 16 + l15][kh]);
#pragma unroll
        for (int mi = 0; mi < 4; mi++)
#pragma unroll
            for (int ni = 0; ni < 4; ni++)
                acc[mi][ni] = __builtin_amdgcn_mfma_f32_16x16x32_bf16(af[mi], bfr[ni], acc[mi][ni], 0, 0, 0);
        __syncthreads();
    }

    const int rb = (lane >> 4) << 2;
    const int cl = lane & 15;
#pragma unroll
    for (int mi = 0; mi < 4; mi++) {
#pragma unroll
        for (int ni = 0; ni < 4; ni++) {
            const int col = n0 + wn * 64 + ni * 16 + cl;
#pragma unroll
            for (int r = 0; r < 4; r++) {
                const int row = m0 + wm * 64 + mi * 16 + rb + r;
                C[(size_t)row * N + col] = acc[mi][ni][r];
            }
        }
    }
}

// ---------------- fp32 SGEMM 128x128, BK=16, 8x8 microtile (o proj, L0 experts) --------
template<bool BT, bool BIAS, bool GELU, bool RESID>
__global__ __launch_bounds__(256) void k_sgemm128(
    const float* __restrict__ A, const float* __restrict__ B,
    const float* __restrict__ bias, const float* __restrict__ resid,
    float* __restrict__ C,
    const int M, const int N, const int K,
    const long long eA, const long long eB, const long long eBias, const long long eC)
{
    const int e = blockIdx.z;
    A += e * eA; B += e * eB; C += e * eC;
    if (BIAS) bias += e * eBias;

    __shared__ __align__(16) float As[16][132];
    __shared__ __align__(16) float Bs[16][132];

    const int tid = threadIdx.x;
    const int ty = tid >> 4;
    const int tx = tid & 15;
    const int m0 = blockIdx.x * 128;
    const int n0 = blockIdx.y * 128;

    const int mA = tid >> 1;
    const int kA = (tid & 1) << 3;
    const int kB = tid >> 4;
    const int nB = (tid & 15) << 3;

    float acc[8][8];
#pragma unroll
    for (int r = 0; r < 8; r++)
#pragma unroll
        for (int c = 0; c < 8; c++) acc[r][c] = 0.f;

    for (int k0 = 0; k0 < K; k0 += 16) {
        {
            const float* ap = A + (size_t)(m0 + mA) * K + k0 + kA;
            const float4 x0 = *reinterpret_cast<const float4*>(ap);
            const float4 x1 = *reinterpret_cast<const float4*>(ap + 4);
            As[kA + 0][mA] = x0.x; As[kA + 1][mA] = x0.y;
            As[kA + 2][mA] = x0.z; As[kA + 3][mA] = x0.w;
            As[kA + 4][mA] = x1.x; As[kA + 5][mA] = x1.y;
            As[kA + 6][mA] = x1.z; As[kA + 7][mA] = x1.w;
        }
        if constexpr (BT) {
            const float* bp = B + (size_t)(n0 + mA) * K + k0 + kA;
            const float4 x0 = *reinterpret_cast<const float4*>(bp);
            const float4 x1 = *reinterpret_cast<const float4*>(bp + 4);
            Bs[kA + 0][mA] = x0.x; Bs[kA + 1][mA] = x0.y;
            Bs[kA + 2][mA] = x0.z; Bs[kA + 3][mA] = x0.w;
            Bs[kA + 4][mA] = x1.x; Bs[kA + 5][mA] = x1.y;
            Bs[kA + 6][mA] = x1.z; Bs[kA + 7][mA] = x1.w;
        } else {
            const float* bp = B + (size_t)(k0 + kB) * N + n0 + nB;
            const float4 x0 = *reinterpret_cast<const float4*>(bp);
            const float4 x1 = *reinterpret_cast<const float4*>(bp + 4);
            *reinterpret_cast<float4*>(&Bs[kB][nB]) = x0;
            *reinterpret_cast<float4*>(&Bs[kB][nB + 4]) = x1;
        }
        __syncthreads();
#pragma unroll 4
        for (int k = 0; k < 16; k++) {
            float a[8], b[8];
            *reinterpret_cast<float4*>(&a[0]) = *reinterpret_cast<const float4*>(&As[k][ty << 2]);
            *reinterpret_cast<float4*>(&a[4]) = *reinterpret_cast<const float4*>(&As[k][64 + (ty << 2)]);
            *reinterpret_cast<float4*>(&b[0]) = *reinterpret_cast<const float4*>(&Bs[k][tx << 2]);
            *reinterpret_cast<float4*>(&b[4]) = *reinterpret_cast<const float4*>(&Bs[k][64 + (tx << 2)]);
#pragma unroll
            for (int r = 0; r < 8; r++)
#pragma unroll
                for (int c = 0; c < 8; c++) acc[r][c] += a[r] * b[c];
        }
        __syncthreads();
    }

#pragma unroll
    for (int rh = 0; rh < 2; rh++) {
#pragma unroll
        for (int r = 0; r < 4; r++) {
            const int ri = (rh << 2) + r;
            const int row = m0 + rh * 64 + (ty << 2) + r;
#pragma unroll
            for (int ch = 0; ch < 2; ch++) {
                const int colb = n0 + ch * 64 + (tx << 2);
                float4 v4;
#pragma unroll
                for (int c = 0; c < 4; c++) {
                    const int ci = (ch << 2) + c;
                    float v = acc[ri][ci];
                    if constexpr (BIAS) v += bias[colb + c];
                    if constexpr (GELU) v = 0.5f * v * (1.f + erff(v * 0.70710678118654752f));
                    if constexpr (RESID) v += resid[(size_t)row * N + colb + c];
                    (&v4.x)[c] = v;
                }
                *reinterpret_cast<float4*>(&C[(size_t)row * N + colb]) = v4;
            }
        }
    }
}

// ---------------- fused QKV projection (sgemm128 math, bit-identical chains) ------------
__global__ __launch_bounds__(256) void k_qkv(
    const float* __restrict__ A, const float* __restrict__ qw,
    const float* __restrict__ kw, const float* __restrict__ vw,
    float* __restrict__ q, float* __restrict__ kf, float* __restrict__ vf)
{
    __shared__ __align__(16) float As[16][132];
    __shared__ __align__(16) float Bs[16][132];

    const int x = blockIdx.x;
    const int m0 = blockIdx.y * 128;
    const int K = HH;

    const int tid = threadIdx.x;
    const int ty = tid >> 4;
    const int tx = tid & 15;
    const int mA = tid >> 1;
    const int kA = (tid & 1) << 3;

    const float* arow = A + (size_t)(m0 + mA) * K + kA;
    const float* brow;
    if (x < 6) brow = qw + (size_t)(x * 128 + mA) * K + kA;
    else       brow = (mA < 64 ? kw + (size_t)mA * K : vw + (size_t)(mA - 64) * K) + kA;

    float acc[8][8];
#pragma unroll
    for (int r = 0; r < 8; r++)
#pragma unroll
        for (int c = 0; c < 8; c++) acc[r][c] = 0.f;

    for (int k0 = 0; k0 < K; k0 += 16) {
        {
            const float4 x0 = *reinterpret_cast<const float4*>(arow + k0);
            const float4 x1 = *reinterpret_cast<const float4*>(arow + k0 + 4);
            As[kA + 0][mA] = x0.x; As[kA + 1][mA] = x0.y;
            As[kA + 2][mA] = x0.z; As[kA + 3][mA] = x0.w;
            As[kA + 4][mA] = x1.x; As[kA + 5][mA] = x1.y;
            As[kA + 6][mA] = x1.z; As[kA + 7][mA] = x1.w;
        }
        {
            const float4 x0 = *reinterpret_cast<const float4*>(brow + k0);
            const float4 x1 = *reinterpret_cast<const float4*>(brow + k0 + 4);
            Bs[kA + 0][mA] = x0.x; Bs[kA + 1][mA] = x0.y;
            Bs[kA + 2][mA] = x0.z; Bs[kA + 3][mA] = x0.w;
            Bs[kA + 4][mA] = x1.x; Bs[kA + 5][mA] = x1.y;
            Bs[kA + 6][mA] = x1.z; Bs[kA + 7][mA] = x1.w;
        }
        __syncthreads();
#pragma unroll 4
        for (int k = 0; k < 16; k++) {
            float a[8], b[8];
            *reinterpret_cast<float4*>(&a[0]) = *reinterpret_cast<const float4*>(&As[k][ty << 2]);
            *reinterpret_cast<float4*>(&a[4]) = *reinterpret_cast<const float4*>(&As[k][64 + (ty << 2)]);
            *reinterpret_cast<float4*>(&b[0]) = *reinterpret_cast<const float4*>(&Bs[k][tx << 2]);
            *reinterpret_cast<float4*>(&b[4]) = *reinterpret_cast<const float4*>(&Bs[k][64 + (tx << 2)]);
#pragma unroll
            for (int r = 0; r < 8; r++)
#pragma unroll
                for (int c = 0; c < 8; c++) acc[r][c] += a[r] * b[c];
        }
        __syncthreads();
    }

#pragma unroll
    for (int rh = 0; rh < 2; rh++) {
#pragma unroll
        for (int r = 0; r < 4; r++) {
            const int ri = (rh << 2) + r;
            const int row = m0 + rh * 64 + (ty << 2) + r;
#pragma unroll
            for (int ch = 0; ch < 2; ch++) {
                float4 v4;
#pragma unroll
                for (int c = 0; c < 4; c++) (&v4.x)[c] = acc[ri][(ch << 2) + c];
                if (x < 6) {
                    const int col = x * 128 + ch * 64 + (tx << 2);
                    *reinterpret_cast<float4*>(&q[(size_t)row * HH + col]) = v4;
                } else {
                    float* dst = (ch == 0) ? kf : vf;
                    *reinterpret_cast<float4*>(&dst[(size_t)row * HDIM + (tx << 2)]) = v4;
                }
            }
        }
    }
}

// ---------------- fp32 flash-tile attention v4: v2 structure + stride-64 XOR-swizzled b128 ----
// slot4(r,c4) = c4 ^ ((r>>2)&7): bijective per row; all accesses 16B-aligned b128.
#define SW4(r, c4) ((((c4) ^ (((r) >> 2) & 7))) << 2)
__global__ __launch_bounds__(256) void k_fattn(const float* __restrict__ q,
                                               const float* __restrict__ kf,
                                               const float* __restrict__ vf,
                                               const float* __restrict__ mask,
                                               float* __restrict__ out) {
    __shared__ __align__(16) float Qs[64][64];
    __shared__ __align__(16) float KP[64][64];   // K-tile, then reused as P-tile
    __shared__ __align__(16) float Vs[64][64];

    const int blk = blockIdx.x;
    const int qt = blk & 31;
    const int bh = blk >> 5;
    const int nh = bh % NHEAD;
    const int b  = bh / NHEAD;
    const int q0 = qt * 64;

    const int tid = threadIdx.x;
    const int ty = tid >> 4;
    const int tx = tid & 15;
    const int sr = tid >> 2;            // staging row 0..63
    const int sc4 = (tid & 3) << 2;     // staging col4 group base 0,4,8,12

    // stage Q (pre-scaled by exact pow2 0.125)
    {
        const float* src = q + (size_t)(b * SEQ + q0 + sr) * HH + nh * HDIM + (sc4 << 2);
#pragma unroll
        for (int i = 0; i < 4; i++) {
            float4 v4 = *reinterpret_cast<const float4*>(src + i * 4);
            v4.x *= 0.125f; v4.y *= 0.125f; v4.z *= 0.125f; v4.w *= 0.125f;
            *reinterpret_cast<float4*>(&Qs[sr][SW4(sr, sc4 + i)]) = v4;
        }
    }

    const float* kb = kf + (size_t)b * SEQ * HDIM;
    const float* vb = vf + (size_t)b * SEQ * HDIM;
    const float* mb = mask + b * SEQ;

    float m[4], l[4], o[4][4];
#pragma unroll
    for (int r = 0; r < 4; r++) {
        m[r] = -3.4028234663852886e38f; l[r] = 0.f;
#pragma unroll
        for (int c = 0; c < 4; c++) o[r][c] = 0.f;
    }

    for (int k0 = 0; k0 < SEQ; k0 += 64) {
        __syncthreads();   // B1: prev PV done reading KP/Vs (and Q staged, first iter)
        // stage K,V direct from global (swizzled b128 writes)
        {
            const float* ksrc = kb + (size_t)(k0 + sr) * HDIM + (sc4 << 2);
            const float* vsrc = vb + (size_t)(k0 + sr) * HDIM + (sc4 << 2);
#pragma unroll
            for (int i = 0; i < 4; i++) {
                *reinterpret_cast<float4*>(&KP[sr][SW4(sr, sc4 + i)]) =
                    *reinterpret_cast<const float4*>(ksrc + i * 4);
                *reinterpret_cast<float4*>(&Vs[sr][SW4(sr, sc4 + i)]) =
                    *reinterpret_cast<const float4*>(vsrc + i * 4);
            }
        }
        __syncthreads();   // B2: tiles ready

        // S = Q K^T
        float s[4][4];
#pragma unroll
        for (int r = 0; r < 4; r++)
#pragma unroll
            for (int c = 0; c < 4; c++) s[r][c] = 0.f;
#pragma unroll 4
        for (int d4 = 0; d4 < 16; d4++) {
            float4 a4[4], b4[4];
#pragma unroll
            for (int r = 0; r < 4; r++) {
                const int row = (ty << 2) + r;
                a4[r] = *reinterpret_cast<const float4*>(&Qs[row][SW4(row, d4)]);
            }
#pragma unroll
            for (int c = 0; c < 4; c++) {
                const int row = (tx << 2) + c;
                b4[c] = *reinterpret_cast<const float4*>(&KP[row][SW4(row, d4)]);
            }
#pragma unroll
            for (int r = 0; r < 4; r++)
#pragma unroll
                for (int c = 0; c < 4; c++)
                    s[r][c] += a4[r].x * b4[c].x + a4[r].y * b4[c].y + a4[r].z * b4[c].z + a4[r].w * b4[c].w;
        }
#pragma unroll
        for (int c = 0; c < 4; c++) {
            const float madd = (1.f - mb[k0 + (tx << 2) + c]) * -3.4028234663852886e38f;
#pragma unroll
            for (int r = 0; r < 4; r++) s[r][c] += madd;
        }
        float tm[4];
#pragma unroll
        for (int r = 0; r < 4; r++) tm[r] = fmaxf(fmaxf(s[r][0], s[r][1]), fmaxf(s[r][2], s[r][3]));
#pragma unroll
        for (int off = 8; off; off >>= 1)
#pragma unroll
            for (int r = 0; r < 4; r++) tm[r] = fmaxf(tm[r], __shfl_xor(tm[r], off));
        float alpha[4], rs[4];
#pragma unroll
        for (int r = 0; r < 4; r++) {
            const float mn = fmaxf(m[r], tm[r]);
            alpha[r] = __expf(m[r] - mn);
            m[r] = mn;
            const float p0 = __expf(s[r][0] - mn);
            const float p1 = __expf(s[r][1] - mn);
            const float p2 = __expf(s[r][2] - mn);
            const float p3 = __expf(s[r][3] - mn);
            s[r][0] = p0; s[r][1] = p1; s[r][2] = p2; s[r][3] = p3;
            rs[r] = (p0 + p1) + (p2 + p3);
        }
#pragma unroll
        for (int off = 8; off; off >>= 1)
#pragma unroll
            for (int r = 0; r < 4; r++) rs[r] += __shfl_xor(rs[r], off);
#pragma unroll
        for (int r = 0; r < 4; r++) l[r] = l[r] * alpha[r] + rs[r];

        __syncthreads();   // B3: all lanes done reading KP as K
        // write P into KP (swizzled b128)
#pragma unroll
        for (int r = 0; r < 4; r++) {
            const int row = (ty << 2) + r;
            *reinterpret_cast<float4*>(&KP[row][SW4(row, tx)]) =
                make_float4(s[r][0], s[r][1], s[r][2], s[r][3]);
        }
        __syncthreads();   // B4: Ps ready

#pragma unroll
        for (int r = 0; r < 4; r++)
#pragma unroll
            for (int c = 0; c < 4; c++) o[r][c] *= alpha[r];
#pragma unroll 4
        for (int kk4 = 0; kk4 < 16; kk4++) {
            float4 p4[4], v40, v41, v42, v43;
#pragma unroll
            for (int r = 0; r < 4; r++) {
                const int row = (ty << 2) + r;
                p4[r] = *reinterpret_cast<const float4*>(&KP[row][SW4(row, kk4)]);
            }
            const int kk0 = kk4 << 2;
            v40 = *reinterpret_cast<const float4*>(&Vs[kk0 + 0][SW4(kk0 + 0, tx)]);
            v41 = *reinterpret_cast<const float4*>(&Vs[kk0 + 1][SW4(kk0 + 1, tx)]);
            v42 = *reinterpret_cast<const float4*>(&Vs[kk0 + 2][SW4(kk0 + 2, tx)]);
            v43 = *reinterpret_cast<const float4*>(&Vs[kk0 + 3][SW4(kk0 + 3, tx)]);
#pragma unroll
            for (int r = 0; r < 4; r++) {
                o[r][0] += p4[r].x * v40.x + p4[r].y * v41.x + p4[r].z * v42.x + p4[r].w * v43.x;
                o[r][1] += p4[r].x * v40.y + p4[r].y * v41.y + p4[r].z * v42.y + p4[r].w * v43.y;
                o[r][2] += p4[r].x * v40.z + p4[r].y * v41.z + p4[r].z * v42.z + p4[r].w * v43.z;
                o[r][3] += p4[r].x * v40.w + p4[r].y * v41.w + p4[r].z * v42.w + p4[r].w * v43.w;
            }
        }
    }

#pragma unroll
    for (int r = 0; r < 4; r++) {
        const float invl = 1.f / l[r];
        const int tq = b * SEQ + q0 + (ty << 2) + r;
        float* dst = out + (size_t)tq * HH + nh * HDIM + (tx << 2);
        *reinterpret_cast<float4*>(dst) =
            make_float4(o[r][0] * invl, o[r][1] * invl, o[r][2] * invl, o[r][3] * invl);
    }
}
#undef SW4

// ---------------- gating: fp32 logits + softmax over 8 experts ----------------
__global__ __launch_bounds__(64) void k_gate(const float* __restrict__ x, const float* __restrict__ gw,
                                             float* __restrict__ scoresT) {
    const int t = blockIdx.x;
    const int lane = threadIdx.x;
    const float* row = x + (size_t)t * HH;
    float acc[8];
#pragma unroll
    for (int e = 0; e < 8; e++) acc[e] = 0.f;
    for (int d = lane; d < HH; d += 64) {
        const float xv = row[d];
#pragma unroll
        for (int e = 0; e < 8; e++) acc[e] += xv * gw[e * HH + d];
    }
#pragma unroll
    for (int e = 0; e < 8; e++) {
#pragma unroll
        for (int off = 32; off; off >>= 1) acc[e] += __shfl_xor(acc[e], off);
    }
    if (lane == 0) {
        float mx = acc[0];
#pragma unroll
        for (int e = 1; e < 8; e++) mx = fmaxf(mx, acc[e]);
        float ex[8], ssum = 0.f;
#pragma unroll
        for (int e = 0; e < 8; e++) { ex[e] = __expf(acc[e] - mx); ssum += ex[e]; }
        const float inv = 1.f / ssum;
#pragma unroll
        for (int e = 0; e < 8; e++) scoresT[(size_t)e * TT + t] = ex[e] * inv;
    }
}

// ---------------- per-expert exact top-640 via bitonic sort (jax tie-break) ----------------
__global__ __launch_bounds__(1024) void k_topk(const float* __restrict__ scoresT,
                                               int* __restrict__ top_i, float* __restrict__ top_s) {
    __shared__ unsigned long long keys[4096];
    const int e = blockIdx.x;
    const int tid = threadIdx.x;
    for (int i = tid; i < 4096; i += 1024) {
        const float sv = scoresT[(size_t)e * TT + i];
        keys[i] = (((unsigned long long)__float_as_uint(sv)) << 32) |
                  (unsigned long long)(0xFFFFFFFFu - (unsigned)i);
    }
    __syncthreads();
    for (int k = 2; k <= 4096; k <<= 1) {
        for (int j = k >> 1; j > 0; j >>= 1) {
            for (int i = tid; i < 4096; i += 1024) {
                const int ixj = i ^ j;
                if (ixj > i) {
                    const bool up = ((i & k) == 0);
                    const unsigned long long a = keys[i], bb = keys[ixj];
                    if ((a > bb) == up) { keys[i] = bb; keys[ixj] = a; }
                }
            }
            __syncthreads();
        }
    }
    for (int c = tid; c < CAP; c += 1024) {
        const unsigned long long u = keys[4095 - c];
        top_i[e * CAP + c] = (int)(0xFFFFFFFFu - (unsigned)(u & 0xFFFFFFFFull));
        top_s[e * CAP + c] = __uint_as_float((unsigned)(u >> 32));
    }
}

// ---------------- explicit gather / scatter for MoE (fp32) ----------------
__global__ __launch_bounds__(192) void k_gather(const int* __restrict__ top_i, const float* __restrict__ hn,
                                                float* __restrict__ xg) {
    const int ec = blockIdx.x;
    const int tok = top_i[ec];
    const float4 v = *reinterpret_cast<const float4*>(hn + (size_t)tok * HH + threadIdx.x * 4);
    *reinterpret_cast<float4*>(xg + (size_t)ec * HH + threadIdx.x * 4) = v;
}

__global__ __launch_bounds__(192) void k_scatter(const int* __restrict__ top_i, const float* __restrict__ top_s,
                                                 const float* __restrict__ oute, float* __restrict__ h) {
    const int ec = blockIdx.x;
    const int tok = top_i[ec];
    const float sc = top_s[ec];
    const float4 v = *reinterpret_cast<const float4*>(oute + (size_t)ec * HH + threadIdx.x * 4);
    float* dst = h + (size_t)tok * HH + threadIdx.x * 4;
    atomicAdd(dst + 0, v.x * sc);
    atomicAdd(dst + 1, v.y * sc);
    atomicAdd(dst + 2, v.z * sc);
    atomicAdd(dst + 3, v.w * sc);
}

__global__ __launch_bounds__(512) void k_lb(const float* __restrict__ top_s, float* __restrict__ lb_out) {
    __shared__ float sums[8];
    const int w = threadIdx.x >> 6, lane = threadIdx.x & 63;
    float s = 0.f;
    for (int c = lane; c < CAP; c += 64) s += top_s[w * CAP + c];
#pragma unroll
    for (int off = 32; off; off >>= 1) s += __shfl_xor(s, off);
    if (lane == 0) sums[w] = s;
    __syncthreads();
    if (threadIdx.x == 0) {
        float mean = 0.f, load[8];
#pragma unroll
        for (int e2 = 0; e2 < 8; e2++) { load[e2] = sums[e2] * (1.f / 4096.f); mean += load[e2]; }
        mean *= 0.125f;
        float var = 0.f;
#pragma unroll
        for (int e2 = 0; e2 < 8; e2++) { const float d = load[e2] - mean; var += d * d; }
        lb_out[0] = var * (1.f / 7.f) * 8.f;
    }
}

__global__ void k_fin(const float* __restrict__ lb, float* __restrict__ dst) {
    if (threadIdx.x == 0 && blockIdx.x == 0) dst[0] = lb[0] + lb[1];
}

extern "C" void kernel_launch(void* const* d_in, const int* in_sizes, int n_in,
                              void* d_out, int out_size, void* d_ws, size_t ws_size,
                              hipStream_t stream)
{
    const int*   ids_raw = (const int*)d_in[0];
    const float* mask  = (const float*)d_in[1];
    const float* embw  = (const float*)d_in[2];
    const float* ln1g  = (const float*)d_in[3];
    const float* ln1b  = (const float*)d_in[4];
    const float* qw    = (const float*)d_in[5];
    const float* kw    = (const float*)d_in[6];
    const float* vw    = (const float*)d_in[7];
    const float* ow    = (const float*)d_in[8];
    const float* ln2g  = (const float*)d_in[9];
    const float* ln2b  = (const float*)d_in[10];
    const float* gw    = (const float*)d_in[11];
    const float* w1    = (const float*)d_in[12];
    const float* b1    = (const float*)d_in[13];
    const float* w2    = (const float*)d_in[14];
    const float* b2    = (const float*)d_in[15];
    const float* lnfg  = (const float*)d_in[16];
    const float* lnfb  = (const float*)d_in[17];
    const float* headw = (const float*)d_in[18];
    float* out = (float*)d_out;

    char* wsb = (char*)d_ws;
    size_t off = 0;
    auto alloc = [&](size_t bytes) -> void* {
        off = (off + 255) & ~(size_t)255;
        void* p = wsb + off;
        off += bytes;
        return p;
    };
    float* h0  = (float*)alloc((size_t)TT * HH * 4);
    float* h1b = (float*)alloc((size_t)TT * HH * 4);
    float* hn  = (float*)alloc((size_t)TT * HH * 4);
    float* q   = (float*)alloc((size_t)TT * HH * 4);
    float* kf  = (float*)alloc((size_t)TT * HDIM * 4);
    float* vf  = (float*)alloc((size_t)TT * HDIM * 4);
    float* scoresT = (float*)alloc((size_t)NEXP * TT * 4);
    int*   idsn    = (int*)alloc((size_t)TT * 4);
    int*   top_i   = (int*)alloc((size_t)NEXP * CAP * 4);
    float* top_s   = (float*)alloc((size_t)NEXP * CAP * 4);
    float* lb      = (float*)alloc(64);
    if (off > ws_size) return;

    // optional bf16 head buffers (ws-gated; bit-identical results either path)
    unsigned short* hnb = (unsigned short*)alloc((size_t)TT * HH * 2);
    unsigned short* hwb = (unsigned short*)alloc((size_t)VOCAB * HH * 2);
    const bool bighead = (off <= ws_size);

    char* outb = (char*)d_out;
    size_t ooff = 0;
    auto oalloc = [&](size_t bytes) -> void* {
        ooff = (ooff + 255) & ~(size_t)255;
        void* p = outb + ooff;
        ooff += bytes;
        return p;
    };
    float* xg   = (float*)oalloc((size_t)NEXP * CAP * HH * 4);
    float* act  = (float*)oalloc((size_t)NEXP * CAP * FDIM * 4);
    float* oute = (float*)oalloc((size_t)NEXP * CAP * HH * 4);

    k_ids<<<16, 256, 0, stream>>>(ids_raw, idsn);
    k_embed<<<TT, 192, 0, stream>>>(idsn, embw, h0);

    float* hc = h0;
    float* ho = h1b;
    for (int l = 0; l < 2; l++) {
        k_ln<<<TT, 64, 0, stream>>>(hc, ln1g + l * HH, ln1b + l * HH, hn);
        k_qkv<<<dim3(7, TT/128), 256, 0, stream>>>(
            hn, qw + (size_t)l * HH * HH, kw + (size_t)l * HDIM * HH, vw + (size_t)l * HDIM * HH,
            q, kf, vf);
        k_fattn<<<2 * NHEAD * (SEQ / 64), 256, 0, stream>>>(q, kf, vf, mask, hn);
        k_sgemm128<true,false,false,true>
            <<<dim3(TT/128, HH/128, 1), 256, 0, stream>>>(
            hn, ow + (size_t)l * HH * HH, nullptr, hc, ho, TT, HH, HH, 0, 0, 0, 0);
        k_ln<<<TT, 64, 0, stream>>>(ho, ln2g + l * HH, ln2b + l * HH, hn);
        k_gate<<<TT, 64, 0, stream>>>(hn, gw + (size_t)l * NEXP * HH, scoresT);
        k_topk<<<NEXP, 1024, 0, stream>>>(scoresT, top_i, top_s);
        k_gather<<<NEXP * CAP, 192, 0, stream>>>(top_i, hn, xg);
        if (l == 1) {
            k_gemm<false,false,true,true,false,float,float>
                <<<dim3(FDIM/64, CAP/64, NEXP), 256, 0, stream>>>(
                xg, w1 + (size_t)l * NEXP * HH * FDIM, b1 + (size_t)l * NEXP * FDIM, nullptr, act,
                CAP, FDIM, HH, (long long)CAP * HH, (long long)HH * FDIM, FDIM, (long long)CAP * FDIM);
            k_gemm<false,false,true,false,false,float,float>
                <<<dim3(HH/64, CAP/64, NEXP), 256, 0, stream>>>(
                act, w2 + (size_t)l * NEXP * FDIM * HH, b2 + (size_t)l * NEXP * HH, nullptr, oute,
                CAP, HH, FDIM, (long long)CAP * FDIM, (long long)FDIM * HH, HH, (long long)CAP * HH);
        } else {
            k_sgemm128<false,true,true,false>
                <<<dim3(CAP/128, FDIM/128, NEXP), 256, 0, stream>>>(
                xg, w1 + (size_t)l * NEXP * HH * FDIM, b1 + (size_t)l * NEXP * FDIM, nullptr, act,
                CAP, FDIM, HH, (long long)CAP * HH, (long long)HH * FDIM, FDIM, (long long)CAP * FDIM);
            k_sgemm128<false,true,false,false>
                <<<dim3(CAP/128, HH/128, NEXP), 256, 0, stream>>>(
                act, w2 + (size_t)l * NEXP * FDIM * HH, b2 + (size_t)l * NEXP * HH, nullptr, oute,
                CAP, HH, FDIM, (long long)CAP * FDIM, (long long)FDIM * HH, HH, (long long)CAP * HH);
        }
        k_scatter<<<NEXP * CAP, 192, 0, stream>>>(top_i, top_s, oute, ho);
        k_lb<<<1, 512, 0, stream>>>(top_s, lb + l);
        float* tmp = hc; hc = ho; ho = tmp;
    }
    k_ln<<<TT, 64, 0, stream>>>(hc, lnfg, lnfb, hn);
    if (bighead) {
        k_tobf<<<(TT * HH / 8 + 255) / 256, 256, 0, stream>>>(hn, hnb, TT * HH / 8);
        k_tobf<<<(VOCAB * HH / 8 + 255) / 256, 256, 0, stream>>>(headw, hwb, VOCAB * HH / 8);
        k_gemm128b<<<dim3(TT/128, VOCAB/128, 1), 256, 0, stream>>>(hnb, hwb, out, TT, VOCAB, HH);
    } else {
        k_gemm128<<<dim3(TT/128, VOCAB/128, 1), 256, 0, stream>>>(hn, headw, out, TT, VOCAB, HH);
    }
    k_fin<<<1, 64, 0, stream>>>(lb, out + (size_t)TT * VOCAB);
}

// Round 12
// 2758.730 us; speedup vs baseline: 1.2208x; 1.0064x over previous
//
#include <hip/hip_runtime.h>
#include <math.h>

#define TT 4096
#define HH 768
#define NHEAD 12
#define HDIM 64
#define NEXP 8
#define FDIM 1536
#define CAP 640
#define SEQ 2048
#define VOCAB 32000

typedef __attribute__((ext_vector_type(4))) float f32x4;
typedef __attribute__((ext_vector_type(8))) short bf16x8;

#define GLD16(gsrc, ldst) __builtin_amdgcn_global_load_lds( \
    (const __attribute__((address_space(1))) void*)(gsrc), \
    (__attribute__((address_space(3))) void*)(ldst), 16, 0, 0)

__device__ __forceinline__ unsigned short f2bf(float f) {
    unsigned int u = __float_as_uint(f);
    unsigned int r = u + 0x7fffu + ((u >> 16) & 1u);
    return (unsigned short)(r >> 16);
}

// --------- input_ids normalize (robust to int32 or int64 host layout) ---------
__global__ __launch_bounds__(256) void k_ids(const int* __restrict__ in, int* __restrict__ outi) {
    __shared__ int is64;
    if (threadIdx.x == 0) {
        int o = 0;
        for (int i = 1; i < 128; i += 2) o |= in[i];
        is64 = (o == 0) ? 1 : 0;
    }
    __syncthreads();
    const int stride = is64 ? 2 : 1;
    for (int t = threadIdx.x + blockIdx.x * 256; t < TT; t += gridDim.x * 256) {
        int v = in[t * stride];
        v = v < 0 ? 0 : (v >= VOCAB ? VOCAB - 1 : v);
        outi[t] = v;
    }
}

__global__ __launch_bounds__(192) void k_embed(const int* __restrict__ ids, const float* __restrict__ ew,
                                               float* __restrict__ h) {
    const int t = blockIdx.x;
    const int id = ids[t];
    const float4* src = reinterpret_cast<const float4*>(ew + (size_t)id * HH);
    float4* dst = reinterpret_cast<float4*>(h + (size_t)t * HH);
    dst[threadIdx.x] = src[threadIdx.x];
}

__global__ __launch_bounds__(64) void k_ln(const float* __restrict__ x, const float* __restrict__ g,
                                           const float* __restrict__ b, float* __restrict__ y) {
    const int t = blockIdx.x;
    const int lane = threadIdx.x;
    const float* row = x + (size_t)t * HH;
    float v[12];
    float s = 0.f, sq = 0.f;
#pragma unroll
    for (int i = 0; i < 12; i++) {
        float f = row[lane + (i << 6)];
        v[i] = f; s += f; sq += f * f;
    }
#pragma unroll
    for (int off = 32; off; off >>= 1) { s += __shfl_xor(s, off); sq += __shfl_xor(sq, off); }
    const float mean = s * (1.f / 768.f);
    float var = sq * (1.f / 768.f) - mean * mean;
    var = fmaxf(var, 0.f);
    const float rstd = rsqrtf(var + 1e-5f);
    float* yr = y + (size_t)t * HH;
#pragma unroll
    for (int i = 0; i < 12; i++) {
        const int d = lane + (i << 6);
        yr[d] = (v[i] - mean) * rstd * g[d] + b[d];
    }
}

// ---------------- fp32 -> bf16 convert (8 elems/thread) ----------------
__global__ __launch_bounds__(256) void k_tobf(const float* __restrict__ in, unsigned short* __restrict__ outb,
                                              const int n8) {
    const int i = blockIdx.x * 256 + threadIdx.x;
    if (i >= n8) return;
    const float4 x0 = *reinterpret_cast<const float4*>(in + (size_t)i * 8);
    const float4 x1 = *reinterpret_cast<const float4*>(in + (size_t)i * 8 + 4);
    ushort4 o0, o1;
    o0.x = f2bf(x0.x); o0.y = f2bf(x0.y); o0.z = f2bf(x0.z); o0.w = f2bf(x0.w);
    o1.x = f2bf(x1.x); o1.y = f2bf(x1.y); o1.z = f2bf(x1.z); o1.w = f2bf(x1.w);
    *reinterpret_cast<ushort4*>(outb + (size_t)i * 8) = o0;
    *reinterpret_cast<ushort4*>(outb + (size_t)i * 8 + 4) = o1;
}

// ---------------- bf16-MFMA GEMM 64x64 (proven): C = A(MxK) * B ----------------
template<bool BT, bool XMAJ, bool BIAS, bool GELU, bool RESID, typename AT, typename OT>
__global__ __launch_bounds__(256) void k_gemm(
    const AT* __restrict__ A, const float* __restrict__ B,
    const float* __restrict__ bias, const float* __restrict__ resid,
    OT* __restrict__ C,
    const int M, const int N, const int K,
    const long long eA, const long long eB, const long long eBias, const long long eC)
{
    const int e = blockIdx.z;
    A += e * eA; B += e * eB; C += e * eC;
    if (BIAS) bias += e * eBias;

    __shared__ __align__(16) short As[64][40];
    __shared__ __align__(16) short Bs[64][40];

    const int tid = threadIdx.x;
    const int lane = tid & 63;
    const int w = tid >> 6;
    const int n0 = (XMAJ ? blockIdx.y : blockIdx.x) * 64;
    const int m0 = (XMAJ ? blockIdx.x : blockIdx.y) * 64;

    f32x4 zero = {0.f, 0.f, 0.f, 0.f};
    f32x4 acc[4];
#pragma unroll
    for (int c = 0; c < 4; c++) acc[c] = zero;

    const int ar = tid >> 2;
    const int ak = (tid & 3) << 3;
    const AT* aptr = A + (size_t)(m0 + ar) * K + ak;

    for (int k0 = 0; k0 < K; k0 += 32) {
        if constexpr (sizeof(AT) == 4) {
            const float* ap = reinterpret_cast<const float*>(aptr) + k0;
            const float4 x0 = *reinterpret_cast<const float4*>(ap);
            const float4 x1 = *reinterpret_cast<const float4*>(ap + 4);
            short* d = &As[ar][ak];
            d[0] = (short)f2bf(x0.x); d[1] = (short)f2bf(x0.y);
            d[2] = (short)f2bf(x0.z); d[3] = (short)f2bf(x0.w);
            d[4] = (short)f2bf(x1.x); d[5] = (short)f2bf(x1.y);
            d[6] = (short)f2bf(x1.z); d[7] = (short)f2bf(x1.w);
        } else {
            const unsigned short* ap = reinterpret_cast<const unsigned short*>(aptr) + k0;
            *reinterpret_cast<int4*>(&As[ar][ak]) = *reinterpret_cast<const int4*>(ap);
        }
        if constexpr (BT) {
            const float* bp = B + (size_t)(n0 + ar) * K + k0 + ak;
            const float4 x0 = *reinterpret_cast<const float4*>(bp);
            const float4 x1 = *reinterpret_cast<const float4*>(bp + 4);
            short* d = &Bs[ar][ak];
            d[0] = (short)f2bf(x0.x); d[1] = (short)f2bf(x0.y);
            d[2] = (short)f2bf(x0.z); d[3] = (short)f2bf(x0.w);
            d[4] = (short)f2bf(x1.x); d[5] = (short)f2bf(x1.y);
            d[6] = (short)f2bf(x1.z); d[7] = (short)f2bf(x1.w);
        } else {
            const int kk = tid >> 6;
            const int nn = tid & 63;
#pragma unroll
            for (int it = 0; it < 8; it++) {
                const int kl = kk + (it << 2);
                Bs[nn][kl] = (short)f2bf(B[(size_t)(k0 + kl) * N + n0 + nn]);
            }
        }
        __syncthreads();
        const bf16x8 af = *reinterpret_cast<const bf16x8*>(&As[(w << 4) + (lane & 15)][(lane >> 4) << 3]);
#pragma unroll
        for (int c = 0; c < 4; c++) {
            const bf16x8 bfr = *reinterpret_cast<const bf16x8*>(&Bs[(c << 4) + (lane & 15)][(lane >> 4) << 3]);
            acc[c] = __builtin_amdgcn_mfma_f32_16x16x32_bf16(af, bfr, acc[c], 0, 0, 0);
        }
        __syncthreads();
    }

    const int rb = (w << 4) + ((lane >> 4) << 2);
    const int cl = lane & 15;
#pragma unroll
    for (int c = 0; c < 4; c++) {
        const int col = n0 + (c << 4) + cl;
        float bv = 0.f;
        if constexpr (BIAS) bv = bias[col];
#pragma unroll
        for (int r = 0; r < 4; r++) {
            const int lrow = m0 + rb + r;
            float v = acc[c][r] + bv;
            if constexpr (GELU) v = 0.5f * v * (1.f + erff(v * 0.70710678118654752f));
            if constexpr (RESID) v += resid[(size_t)lrow * N + col];
            if constexpr (sizeof(OT) == 2) {
                C[(size_t)lrow * N + col] = (OT)f2bf(v);
            } else {
                C[(size_t)lrow * N + col] = v;
            }
        }
    }
}

// ---------------- bf16-MFMA GEMM 128x128 fp32-in (head fallback): C = A*B^T ----------------
__global__ __launch_bounds__(256) void k_gemm128(
    const float* __restrict__ A, const float* __restrict__ B, float* __restrict__ C,
    const int M, const int N, const int K)
{
    __shared__ __align__(16) short As[128][40];
    __shared__ __align__(16) short Bs[128][40];

    const int tid = threadIdx.x;
    const int lane = tid & 63;
    const int w = tid >> 6;
    const int wm = w >> 1, wn = w & 1;
    const int m0 = blockIdx.x * 128, n0 = blockIdx.y * 128;

    f32x4 zero = {0.f, 0.f, 0.f, 0.f};
    f32x4 acc[4][4];
#pragma unroll
    for (int mi = 0; mi < 4; mi++)
#pragma unroll
        for (int ni = 0; ni < 4; ni++) acc[mi][ni] = zero;

    const int srow = tid >> 1;
    const int sk = (tid & 1) << 4;
    const float* aptr = A + (size_t)(m0 + srow) * K + sk;
    const float* bptr = B + (size_t)(n0 + srow) * K + sk;

    const int kh = (lane >> 4) << 3;
    const int l15 = lane & 15;

    for (int k0 = 0; k0 < K; k0 += 32) {
        {
            const float4 a0 = *reinterpret_cast<const float4*>(aptr + k0);
            const float4 a1 = *reinterpret_cast<const float4*>(aptr + k0 + 4);
            const float4 a2 = *reinterpret_cast<const float4*>(aptr + k0 + 8);
            const float4 a3 = *reinterpret_cast<const float4*>(aptr + k0 + 12);
            short* d = &As[srow][sk];
            d[0]  = (short)f2bf(a0.x); d[1]  = (short)f2bf(a0.y);
            d[2]  = (short)f2bf(a0.z); d[3]  = (short)f2bf(a0.w);
            d[4]  = (short)f2bf(a1.x); d[5]  = (short)f2bf(a1.y);
            d[6]  = (short)f2bf(a1.z); d[7]  = (short)f2bf(a1.w);
            d[8]  = (short)f2bf(a2.x); d[9]  = (short)f2bf(a2.y);
            d[10] = (short)f2bf(a2.z); d[11] = (short)f2bf(a2.w);
            d[12] = (short)f2bf(a3.x); d[13] = (short)f2bf(a3.y);
            d[14] = (short)f2bf(a3.z); d[15] = (short)f2bf(a3.w);
            const float4 b0 = *reinterpret_cast<const float4*>(bptr + k0);
            const float4 b1 = *reinterpret_cast<const float4*>(bptr + k0 + 4);
            const float4 b2 = *reinterpret_cast<const float4*>(bptr + k0 + 8);
            const float4 b3 = *reinterpret_cast<const float4*>(bptr + k0 + 12);
            short* e = &Bs[srow][sk];
            e[0]  = (short)f2bf(b0.x); e[1]  = (short)f2bf(b0.y);
            e[2]  = (short)f2bf(b0.z); e[3]  = (short)f2bf(b0.w);
            e[4]  = (short)f2bf(b1.x); e[5]  = (short)f2bf(b1.y);
            e[6]  = (short)f2bf(b1.z); e[7]  = (short)f2bf(b1.w);
            e[8]  = (short)f2bf(b2.x); e[9]  = (short)f2bf(b2.y);
            e[10] = (short)f2bf(b2.z); e[11] = (short)f2bf(b2.w);
            e[12] = (short)f2bf(b3.x); e[13] = (short)f2bf(b3.y);
            e[14] = (short)f2bf(b3.z); e[15] = (short)f2bf(b3.w);
        }
        __syncthreads();
        bf16x8 af[4], bfr[4];
#pragma unroll
        for (int mi = 0; mi < 4; mi++)
            af[mi] = *reinterpret_cast<const bf16x8*>(&As[wm * 64 + mi * 16 + l15][kh]);
#pragma unroll
        for (int ni = 0; ni < 4; ni++)
            bfr[ni] = *reinterpret_cast<const bf16x8*>(&Bs[wn * 64 + ni * 16 + l15][kh]);
#pragma unroll
        for (int mi = 0; mi < 4; mi++)
#pragma unroll
            for (int ni = 0; ni < 4; ni++)
                acc[mi][ni] = __builtin_amdgcn_mfma_f32_16x16x32_bf16(af[mi], bfr[ni], acc[mi][ni], 0, 0, 0);
        __syncthreads();
    }

    const int rb = (lane >> 4) << 2;
    const int cl = lane & 15;
#pragma unroll
    for (int mi = 0; mi < 4; mi++) {
#pragma unroll
        for (int ni = 0; ni < 4; ni++) {
            const int col = n0 + wn * 64 + ni * 16 + cl;
#pragma unroll
            for (int r = 0; r < 4; r++) {
                const int row = m0 + wm * 64 + mi * 16 + rb + r;
                C[(size_t)row * N + col] = acc[mi][ni][r];
            }
        }
    }
}

// ---------------- bf16-MFMA GEMM 128x128, pre-converted bf16 (reg-staged; kept for revert) ---
__global__ __launch_bounds__(256) void k_gemm128b(
    const unsigned short* __restrict__ A, const unsigned short* __restrict__ B, float* __restrict__ C,
    const int M, const int N, const int K)
{
    __shared__ __align__(16) short As[128][40];
    __shared__ __align__(16) short Bs[128][40];

    const int tid = threadIdx.x;
    const int lane = tid & 63;
    const int w = tid >> 6;
    const int wm = w >> 1, wn = w & 1;
    const int m0 = blockIdx.x * 128, n0 = blockIdx.y * 128;

    f32x4 zero = {0.f, 0.f, 0.f, 0.f};
    f32x4 acc[4][4];
#pragma unroll
    for (int mi = 0; mi < 4; mi++)
#pragma unroll
        for (int ni = 0; ni < 4; ni++) acc[mi][ni] = zero;

    const int srow = tid >> 1;
    const int sk = (tid & 1) << 4;
    const unsigned short* aptr = A + (size_t)(m0 + srow) * K + sk;
    const unsigned short* bptr = B + (size_t)(n0 + srow) * K + sk;

    const int kh = (lane >> 4) << 3;
    const int l15 = lane & 15;

    for (int k0 = 0; k0 < K; k0 += 32) {
        {
            const int4* a4 = reinterpret_cast<const int4*>(aptr + k0);
            *reinterpret_cast<int4*>(&As[srow][sk]) = a4[0];
            *reinterpret_cast<int4*>(&As[srow][sk + 8]) = a4[1];
            const int4* b4 = reinterpret_cast<const int4*>(bptr + k0);
            *reinterpret_cast<int4*>(&Bs[srow][sk]) = b4[0];
            *reinterpret_cast<int4*>(&Bs[srow][sk + 8]) = b4[1];
        }
        __syncthreads();
        bf16x8 af[4], bfr[4];
#pragma unroll
        for (int mi = 0; mi < 4; mi++)
            af[mi] = *reinterpret_cast<const bf16x8*>(&As[wm * 64 + mi * 16 + l15][kh]);
#pragma unroll
        for (int ni = 0; ni < 4; ni++)
            bfr[ni] = *reinterpret_cast<const bf16x8*>(&Bs[wn * 64 + ni * 16 + l15][kh]);
#pragma unroll
        for (int mi = 0; mi < 4; mi++)
#pragma unroll
            for (int ni = 0; ni < 4; ni++)
                acc[mi][ni] = __builtin_amdgcn_mfma_f32_16x16x32_bf16(af[mi], bfr[ni], acc[mi][ni], 0, 0, 0);
        __syncthreads();
    }

    const int rb = (lane >> 4) << 2;
    const int cl = lane & 15;
#pragma unroll
    for (int mi = 0; mi < 4; mi++) {
#pragma unroll
        for (int ni = 0; ni < 4; ni++) {
            const int col = n0 + wn * 64 + ni * 16 + cl;
#pragma unroll
            for (int r = 0; r < 4; r++) {
                const int row = m0 + wm * 64 + mi * 16 + rb + r;
                C[(size_t)row * N + col] = acc[mi][ni][r];
            }
        }
    }
}

// ---------------- bf16-MFMA GEMM 128x128, global_load_lds + chunk swizzle (head fast) -------
// LDS chunk(row,j) = row*4 + (j ^ ((row>>1)&3)); linear gload_lds writes, conflict-free reads.
__global__ __launch_bounds__(256) void k_gemm128g(
    const unsigned short* __restrict__ A, const unsigned short* __restrict__ B, float* __restrict__ C,
    const int M, const int N, const int K)
{
    __shared__ __align__(16) unsigned short As[4096];   // 512 chunks x 8 shorts
    __shared__ __align__(16) unsigned short Bs[4096];

    const int tid = threadIdx.x;
    const int lane = tid & 63;
    const int w = tid >> 6;
    const int wm = w >> 1, wn = w & 1;
    const int m0 = blockIdx.x * 128, n0 = blockIdx.y * 128;

    f32x4 zero = {0.f, 0.f, 0.f, 0.f};
    f32x4 acc[4][4];
#pragma unroll
    for (int mi = 0; mi < 4; mi++)
#pragma unroll
        for (int ni = 0; ni < 4; ni++) acc[mi][ni] = zero;

    // staging: thread handles chunks p0 = w*64+lane and p1 = p0+256
    const int p0 = (w << 6) + lane;
    const int p1 = p0 + 256;
    const int row0 = p0 >> 2, j0 = (p0 & 3) ^ ((row0 >> 1) & 3);
    const int row1 = p1 >> 2, j1 = (p1 & 3) ^ ((row1 >> 1) & 3);
    const unsigned short* a0 = A + (size_t)(m0 + row0) * K + (j0 << 3);
    const unsigned short* a1 = A + (size_t)(m0 + row1) * K + (j1 << 3);
    const unsigned short* b0 = B + (size_t)(n0 + row0) * K + (j0 << 3);
    const unsigned short* b1 = B + (size_t)(n0 + row1) * K + (j1 << 3);
    unsigned short* asd0 = &As[(size_t)(w << 6) * 8];
    unsigned short* asd1 = &As[(size_t)((w << 6) + 256) * 8];
    unsigned short* bsd0 = &Bs[(size_t)(w << 6) * 8];
    unsigned short* bsd1 = &Bs[(size_t)((w << 6) + 256) * 8];

    const int jf = lane >> 4;       // fragment k-half 0..3
    const int l15 = lane & 15;

    for (int k0 = 0; k0 < K; k0 += 32) {
        GLD16(a0 + k0, asd0);
        GLD16(a1 + k0, asd1);
        GLD16(b0 + k0, bsd0);
        GLD16(b1 + k0, bsd1);
        __syncthreads();    // drains vmcnt (gload_lds) + sync

        bf16x8 af[4], bfr[4];
#pragma unroll
        for (int mi = 0; mi < 4; mi++) {
            const int row = wm * 64 + mi * 16 + l15;
            const int ch = (row << 2) + (jf ^ ((row >> 1) & 3));
            af[mi] = *reinterpret_cast<const bf16x8*>(&As[ch << 3]);
        }
#pragma unroll
        for (int ni = 0; ni < 4; ni++) {
            const int row = wn * 64 + ni * 16 + l15;
            const int ch = (row << 2) + (jf ^ ((row >> 1) & 3));
            bfr[ni] = *reinterpret_cast<const bf16x8*>(&Bs[ch << 3]);
        }
#pragma unroll
        for (int mi = 0; mi < 4; mi++)
#pragma unroll
            for (int ni = 0; ni < 4; ni++)
                acc[mi][ni] = __builtin_amdgcn_mfma_f32_16x16x32_bf16(af[mi], bfr[ni], acc[mi][ni], 0, 0, 0);
        __syncthreads();    // all reads done before next tile's loads land
    }

    const int rb = (lane >> 4) << 2;
    const int cl = lane & 15;
#pragma unroll
    for (int mi = 0; mi < 4; mi++) {
#pragma unroll
        for (int ni = 0; ni < 4; ni++) {
            const int col = n0 + wn * 64 + ni * 16 + cl;
#pragma unroll
            for (int r = 0; r < 4; r++) {
                const int row = m0 + wm * 64 + mi * 16 + rb + r;
                C[(size_t)row * N + col] = acc[mi][ni][r];
            }
        }
    }
}

// ---------------- fp32 SGEMM 128x128, BK=16, 8x8 microtile (o proj, L0 experts) --------
template<bool BT, bool BIAS, bool GELU, bool RESID>
__global__ __launch_bounds__(256) void k_sgemm128(
    const float* __restrict__ A, const float* __restrict__ B,
    const float* __restrict__ bias, const float* __restrict__ resid,
    float* __restrict__ C,
    const int M, const int N, const int K,
    const long long eA, const long long eB, const long long eBias, const long long eC)
{
    const int e = blockIdx.z;
    A += e * eA; B += e * eB; C += e * eC;
    if (BIAS) bias += e * eBias;

    __shared__ __align__(16) float As[16][132];
    __shared__ __align__(16) float Bs[16][132];

    const int tid = threadIdx.x;
    const int ty = tid >> 4;
    const int tx = tid & 15;
    const int m0 = blockIdx.x * 128;
    const int n0 = blockIdx.y * 128;

    const int mA = tid >> 1;
    const int kA = (tid & 1) << 3;
    const int kB = tid >> 4;
    const int nB = (tid & 15) << 3;

    float acc[8][8];
#pragma unroll
    for (int r = 0; r < 8; r++)
#pragma unroll
        for (int c = 0; c < 8; c++) acc[r][c] = 0.f;

    for (int k0 = 0; k0 < K; k0 += 16) {
        {
            const float* ap = A + (size_t)(m0 + mA) * K + k0 + kA;
            const float4 x0 = *reinterpret_cast<const float4*>(ap);
            const float4 x1 = *reinterpret_cast<const float4*>(ap + 4);
            As[kA + 0][mA] = x0.x; As[kA + 1][mA] = x0.y;
            As[kA + 2][mA] = x0.z; As[kA + 3][mA] = x0.w;
            As[kA + 4][mA] = x1.x; As[kA + 5][mA] = x1.y;
            As[kA + 6][mA] = x1.z; As[kA + 7][mA] = x1.w;
        }
        if constexpr (BT) {
            const float* bp = B + (size_t)(n0 + mA) * K + k0 + kA;
            const float4 x0 = *reinterpret_cast<const float4*>(bp);
            const float4 x1 = *reinterpret_cast<const float4*>(bp + 4);
            Bs[kA + 0][mA] = x0.x; Bs[kA + 1][mA] = x0.y;
            Bs[kA + 2][mA] = x0.z; Bs[kA + 3][mA] = x0.w;
            Bs[kA + 4][mA] = x1.x; Bs[kA + 5][mA] = x1.y;
            Bs[kA + 6][mA] = x1.z; Bs[kA + 7][mA] = x1.w;
        } else {
            const float* bp = B + (size_t)(k0 + kB) * N + n0 + nB;
            const float4 x0 = *reinterpret_cast<const float4*>(bp);
            const float4 x1 = *reinterpret_cast<const float4*>(bp + 4);
            *reinterpret_cast<float4*>(&Bs[kB][nB]) = x0;
            *reinterpret_cast<float4*>(&Bs[kB][nB + 4]) = x1;
        }
        __syncthreads();
#pragma unroll 4
        for (int k = 0; k < 16; k++) {
            float a[8], b[8];
            *reinterpret_cast<float4*>(&a[0]) = *reinterpret_cast<const float4*>(&As[k][ty << 2]);
            *reinterpret_cast<float4*>(&a[4]) = *reinterpret_cast<const float4*>(&As[k][64 + (ty << 2)]);
            *reinterpret_cast<float4*>(&b[0]) = *reinterpret_cast<const float4*>(&Bs[k][tx << 2]);
            *reinterpret_cast<float4*>(&b[4]) = *reinterpret_cast<const float4*>(&Bs[k][64 + (tx << 2)]);
#pragma unroll
            for (int r = 0; r < 8; r++)
#pragma unroll
                for (int c = 0; c < 8; c++) acc[r][c] += a[r] * b[c];
        }
        __syncthreads();
    }

#pragma unroll
    for (int rh = 0; rh < 2; rh++) {
#pragma unroll
        for (int r = 0; r < 4; r++) {
            const int ri = (rh << 2) + r;
            const int row = m0 + rh * 64 + (ty << 2) + r;
#pragma unroll
            for (int ch = 0; ch < 2; ch++) {
                const int colb = n0 + ch * 64 + (tx << 2);
                float4 v4;
#pragma unroll
                for (int c = 0; c < 4; c++) {
                    const int ci = (ch << 2) + c;
                    float v = acc[ri][ci];
                    if constexpr (BIAS) v += bias[colb + c];
                    if constexpr (GELU) v = 0.5f * v * (1.f + erff(v * 0.70710678118654752f));
                    if constexpr (RESID) v += resid[(size_t)row * N + colb + c];
                    (&v4.x)[c] = v;
                }
                *reinterpret_cast<float4*>(&C[(size_t)row * N + colb]) = v4;
            }
        }
    }
}

// ---------------- fused QKV projection (sgemm128 math, bit-identical chains) ------------
__global__ __launch_bounds__(256) void k_qkv(
    const float* __restrict__ A, const float* __restrict__ qw,
    const float* __restrict__ kw, const float* __restrict__ vw,
    float* __restrict__ q, float* __restrict__ kf, float* __restrict__ vf)
{
    __shared__ __align__(16) float As[16][132];
    __shared__ __align__(16) float Bs[16][132];

    const int x = blockIdx.x;
    const int m0 = blockIdx.y * 128;
    const int K = HH;

    const int tid = threadIdx.x;
    const int ty = tid >> 4;
    const int tx = tid & 15;
    const int mA = tid >> 1;
    const int kA = (tid & 1) << 3;

    const float* arow = A + (size_t)(m0 + mA) * K + kA;
    const float* brow;
    if (x < 6) brow = qw + (size_t)(x * 128 + mA) * K + kA;
    else       brow = (mA < 64 ? kw + (size_t)mA * K : vw + (size_t)(mA - 64) * K) + kA;

    float acc[8][8];
#pragma unroll
    for (int r = 0; r < 8; r++)
#pragma unroll
        for (int c = 0; c < 8; c++) acc[r][c] = 0.f;

    for (int k0 = 0; k0 < K; k0 += 16) {
        {
            const float4 x0 = *reinterpret_cast<const float4*>(arow + k0);
            const float4 x1 = *reinterpret_cast<const float4*>(arow + k0 + 4);
            As[kA + 0][mA] = x0.x; As[kA + 1][mA] = x0.y;
            As[kA + 2][mA] = x0.z; As[kA + 3][mA] = x0.w;
            As[kA + 4][mA] = x1.x; As[kA + 5][mA] = x1.y;
            As[kA + 6][mA] = x1.z; As[kA + 7][mA] = x1.w;
        }
        {
            const float4 x0 = *reinterpret_cast<const float4*>(brow + k0);
            const float4 x1 = *reinterpret_cast<const float4*>(brow + k0 + 4);
            Bs[kA + 0][mA] = x0.x; Bs[kA + 1][mA] = x0.y;
            Bs[kA + 2][mA] = x0.z; Bs[kA + 3][mA] = x0.w;
            Bs[kA + 4][mA] = x1.x; Bs[kA + 5][mA] = x1.y;
            Bs[kA + 6][mA] = x1.z; Bs[kA + 7][mA] = x1.w;
        }
        __syncthreads();
#pragma unroll 4
        for (int k = 0; k < 16; k++) {
            float a[8], b[8];
            *reinterpret_cast<float4*>(&a[0]) = *reinterpret_cast<const float4*>(&As[k][ty << 2]);
            *reinterpret_cast<float4*>(&a[4]) = *reinterpret_cast<const float4*>(&As[k][64 + (ty << 2)]);
            *reinterpret_cast<float4*>(&b[0]) = *reinterpret_cast<const float4*>(&Bs[k][tx << 2]);
            *reinterpret_cast<float4*>(&b[4]) = *reinterpret_cast<const float4*>(&Bs[k][64 + (tx << 2)]);
#pragma unroll
            for (int r = 0; r < 8; r++)
#pragma unroll
                for (int c = 0; c < 8; c++) acc[r][c] += a[r] * b[c];
        }
        __syncthreads();
    }

#pragma unroll
    for (int rh = 0; rh < 2; rh++) {
#pragma unroll
        for (int r = 0; r < 4; r++) {
            const int ri = (rh << 2) + r;
            const int row = m0 + rh * 64 + (ty << 2) + r;
#pragma unroll
            for (int ch = 0; ch < 2; ch++) {
                float4 v4;
#pragma unroll
                for (int c = 0; c < 4; c++) (&v4.x)[c] = acc[ri][(ch << 2) + c];
                if (x < 6) {
                    const int col = x * 128 + ch * 64 + (tx << 2);
                    *reinterpret_cast<float4*>(&q[(size_t)row * HH + col]) = v4;
                } else {
                    float* dst = (ch == 0) ? kf : vf;
                    *reinterpret_cast<float4*>(&dst[(size_t)row * HDIM + (tx << 2)]) = v4;
                }
            }
        }
    }
}

// ---------------- fp32 flash-tile attention v4: stride-64 XOR-swizzled b128 (proven) ----
#define SW4(r, c4) ((((c4) ^ (((r) >> 2) & 7))) << 2)
__global__ __launch_bounds__(256) void k_fattn(const float* __restrict__ q,
                                               const float* __restrict__ kf,
                                               const float* __restrict__ vf,
                                               const float* __restrict__ mask,
                                               float* __restrict__ out) {
    __shared__ __align__(16) float Qs[64][64];
    __shared__ __align__(16) float KP[64][64];   // K-tile, then reused as P-tile
    __shared__ __align__(16) float Vs[64][64];

    const int blk = blockIdx.x;
    const int qt = blk & 31;
    const int bh = blk >> 5;
    const int nh = bh % NHEAD;
    const int b  = bh / NHEAD;
    const int q0 = qt * 64;

    const int tid = threadIdx.x;
    const int ty = tid >> 4;
    const int tx = tid & 15;
    const int sr = tid >> 2;
    const int sc4 = (tid & 3) << 2;

    {
        const float* src = q + (size_t)(b * SEQ + q0 + sr) * HH + nh * HDIM + (sc4 << 2);
#pragma unroll
        for (int i = 0; i < 4; i++) {
            float4 v4 = *reinterpret_cast<const float4*>(src + i * 4);
            v4.x *= 0.125f; v4.y *= 0.125f; v4.z *= 0.125f; v4.w *= 0.125f;
            *reinterpret_cast<float4*>(&Qs[sr][SW4(sr, sc4 + i)]) = v4;
        }
    }

    const float* kb = kf + (size_t)b * SEQ * HDIM;
    const float* vb = vf + (size_t)b * SEQ * HDIM;
    const float* mb = mask + b * SEQ;

    float m[4], l[4], o[4][4];
#pragma unroll
    for (int r = 0; r < 4; r++) {
        m[r] = -3.4028234663852886e38f; l[r] = 0.f;
#pragma unroll
        for (int c = 0; c < 4; c++) o[r][c] = 0.f;
    }

    for (int k0 = 0; k0 < SEQ; k0 += 64) {
        __syncthreads();
        {
            const float* ksrc = kb + (size_t)(k0 + sr) * HDIM + (sc4 << 2);
            const float* vsrc = vb + (size_t)(k0 + sr) * HDIM + (sc4 << 2);
#pragma unroll
            for (int i = 0; i < 4; i++) {
                *reinterpret_cast<float4*>(&KP[sr][SW4(sr, sc4 + i)]) =
                    *reinterpret_cast<const float4*>(ksrc + i * 4);
                *reinterpret_cast<float4*>(&Vs[sr][SW4(sr, sc4 + i)]) =
                    *reinterpret_cast<const float4*>(vsrc + i * 4);
            }
        }
        __syncthreads();

        float s[4][4];
#pragma unroll
        for (int r = 0; r < 4; r++)
#pragma unroll
            for (int c = 0; c < 4; c++) s[r][c] = 0.f;
#pragma unroll 4
        for (int d4 = 0; d4 < 16; d4++) {
            float4 a4[4], b4[4];
#pragma unroll
            for (int r = 0; r < 4; r++) {
                const int row = (ty << 2) + r;
                a4[r] = *reinterpret_cast<const float4*>(&Qs[row][SW4(row, d4)]);
            }
#pragma unroll
            for (int c = 0; c < 4; c++) {
                const int row = (tx << 2) + c;
                b4[c] = *reinterpret_cast<const float4*>(&KP[row][SW4(row, d4)]);
            }
#pragma unroll
            for (int r = 0; r < 4; r++)
#pragma unroll
                for (int c = 0; c < 4; c++)
                    s[r][c] += a4[r].x * b4[c].x + a4[r].y * b4[c].y + a4[r].z * b4[c].z + a4[r].w * b4[c].w;
        }
#pragma unroll
        for (int c = 0; c < 4; c++) {
            const float madd = (1.f - mb[k0 + (tx << 2) + c]) * -3.4028234663852886e38f;
#pragma unroll
            for (int r = 0; r < 4; r++) s[r][c] += madd;
        }
        float tm[4];
#pragma unroll
        for (int r = 0; r < 4; r++) tm[r] = fmaxf(fmaxf(s[r][0], s[r][1]), fmaxf(s[r][2], s[r][3]));
#pragma unroll
        for (int off = 8; off; off >>= 1)
#pragma unroll
            for (int r = 0; r < 4; r++) tm[r] = fmaxf(tm[r], __shfl_xor(tm[r], off));
        float alpha[4], rs[4];
#pragma unroll
        for (int r = 0; r < 4; r++) {
            const float mn = fmaxf(m[r], tm[r]);
            alpha[r] = __expf(m[r] - mn);
            m[r] = mn;
            const float p0 = __expf(s[r][0] - mn);
            const float p1 = __expf(s[r][1] - mn);
            const float p2 = __expf(s[r][2] - mn);
            const float p3 = __expf(s[r][3] - mn);
            s[r][0] = p0; s[r][1] = p1; s[r][2] = p2; s[r][3] = p3;
            rs[r] = (p0 + p1) + (p2 + p3);
        }
#pragma unroll
        for (int off = 8; off; off >>= 1)
#pragma unroll
            for (int r = 0; r < 4; r++) rs[r] += __shfl_xor(rs[r], off);
#pragma unroll
        for (int r = 0; r < 4; r++) l[r] = l[r] * alpha[r] + rs[r];

        __syncthreads();
#pragma unroll
        for (int r = 0; r < 4; r++) {
            const int row = (ty << 2) + r;
            *reinterpret_cast<float4*>(&KP[row][SW4(row, tx)]) =
                make_float4(s[r][0], s[r][1], s[r][2], s[r][3]);
        }
        __syncthreads();

#pragma unroll
        for (int r = 0; r < 4; r++)
#pragma unroll
            for (int c = 0; c < 4; c++) o[r][c] *= alpha[r];
#pragma unroll 4
        for (int kk4 = 0; kk4 < 16; kk4++) {
            float4 p4[4], v40, v41, v42, v43;
#pragma unroll
            for (int r = 0; r < 4; r++) {
                const int row = (ty << 2) + r;
                p4[r] = *reinterpret_cast<const float4*>(&KP[row][SW4(row, kk4)]);
            }
            const int kk0 = kk4 << 2;
            v40 = *reinterpret_cast<const float4*>(&Vs[kk0 + 0][SW4(kk0 + 0, tx)]);
            v41 = *reinterpret_cast<const float4*>(&Vs[kk0 + 1][SW4(kk0 + 1, tx)]);
            v42 = *reinterpret_cast<const float4*>(&Vs[kk0 + 2][SW4(kk0 + 2, tx)]);
            v43 = *reinterpret_cast<const float4*>(&Vs[kk0 + 3][SW4(kk0 + 3, tx)]);
#pragma unroll
            for (int r = 0; r < 4; r++) {
                o[r][0] += p4[r].x * v40.x + p4[r].y * v41.x + p4[r].z * v42.x + p4[r].w * v43.x;
                o[r][1] += p4[r].x * v40.y + p4[r].y * v41.y + p4[r].z * v42.y + p4[r].w * v43.y;
                o[r][2] += p4[r].x * v40.z + p4[r].y * v41.z + p4[r].z * v42.z + p4[r].w * v43.z;
                o[r][3] += p4[r].x * v40.w + p4[r].y * v41.w + p4[r].z * v42.w + p4[r].w * v43.w;
            }
        }
    }

#pragma unroll
    for (int r = 0; r < 4; r++) {
        const float invl = 1.f / l[r];
        const int tq = b * SEQ + q0 + (ty << 2) + r;
        float* dst = out + (size_t)tq * HH + nh * HDIM + (tx << 2);
        *reinterpret_cast<float4*>(dst) =
            make_float4(o[r][0] * invl, o[r][1] * invl, o[r][2] * invl, o[r][3] * invl);
    }
}
#undef SW4

// ---------------- gating: fp32 logits + softmax over 8 experts ----------------
__global__ __launch_bounds__(64) void k_gate(const float* __restrict__ x, const float* __restrict__ gw,
                                             float* __restrict__ scoresT) {
    const int t = blockIdx.x;
    const int lane = threadIdx.x;
    const float* row = x + (size_t)t * HH;
    float acc[8];
#pragma unroll
    for (int e = 0; e < 8; e++) acc[e] = 0.f;
    for (int d = lane; d < HH; d += 64) {
        const float xv = row[d];
#pragma unroll
        for (int e = 0; e < 8; e++) acc[e] += xv * gw[e * HH + d];
    }
#pragma unroll
    for (int e = 0; e < 8; e++) {
#pragma unroll
        for (int off = 32; off; off >>= 1) acc[e] += __shfl_xor(acc[e], off);
    }
    if (lane == 0) {
        float mx = acc[0];
#pragma unroll
        for (int e = 1; e < 8; e++) mx = fmaxf(mx, acc[e]);
        float ex[8], ssum = 0.f;
#pragma unroll
        for (int e = 0; e < 8; e++) { ex[e] = __expf(acc[e] - mx); ssum += ex[e]; }
        const float inv = 1.f / ssum;
#pragma unroll
        for (int e = 0; e < 8; e++) scoresT[(size_t)e * TT + t] = ex[e] * inv;
    }
}

// ---------------- per-expert exact top-640 via bitonic sort (jax tie-break) ----------------
__global__ __launch_bounds__(1024) void k_topk(const float* __restrict__ scoresT,
                                               int* __restrict__ top_i, float* __restrict__ top_s) {
    __shared__ unsigned long long keys[4096];
    const int e = blockIdx.x;
    const int tid = threadIdx.x;
    for (int i = tid; i < 4096; i += 1024) {
        const float sv = scoresT[(size_t)e * TT + i];
        keys[i] = (((unsigned long long)__float_as_uint(sv)) << 32) |
                  (unsigned long long)(0xFFFFFFFFu - (unsigned)i);
    }
    __syncthreads();
    for (int k = 2; k <= 4096; k <<= 1) {
        for (int j = k >> 1; j > 0; j >>= 1) {
            for (int i = tid; i < 4096; i += 1024) {
                const int ixj = i ^ j;
                if (ixj > i) {
                    const bool up = ((i & k) == 0);
                    const unsigned long long a = keys[i], bb = keys[ixj];
                    if ((a > bb) == up) { keys[i] = bb; keys[ixj] = a; }
                }
            }
            __syncthreads();
        }
    }
    for (int c = tid; c < CAP; c += 1024) {
        const unsigned long long u = keys[4095 - c];
        top_i[e * CAP + c] = (int)(0xFFFFFFFFu - (unsigned)(u & 0xFFFFFFFFull));
        top_s[e * CAP + c] = __uint_as_float((unsigned)(u >> 32));
    }
}

// ---------------- explicit gather / scatter for MoE (fp32) ----------------
__global__ __launch_bounds__(192) void k_gather(const int* __restrict__ top_i, const float* __restrict__ hn,
                                                float* __restrict__ xg) {
    const int ec = blockIdx.x;
    const int tok = top_i[ec];
    const float4 v = *reinterpret_cast<const float4*>(hn + (size_t)tok * HH + threadIdx.x * 4);
    *reinterpret_cast<float4*>(xg + (size_t)ec * HH + threadIdx.x * 4) = v;
}

__global__ __launch_bounds__(192) void k_scatter(const int* __restrict__ top_i, const float* __restrict__ top_s,
                                                 const float* __restrict__ oute, float* __restrict__ h) {
    const int ec = blockIdx.x;
    const int tok = top_i[ec];
    const float sc = top_s[ec];
    const float4 v = *reinterpret_cast<const float4*>(oute + (size_t)ec * HH + threadIdx.x * 4);
    float* dst = h + (size_t)tok * HH + threadIdx.x * 4;
    atomicAdd(dst + 0, v.x * sc);
    atomicAdd(dst + 1, v.y * sc);
    atomicAdd(dst + 2, v.z * sc);
    atomicAdd(dst + 3, v.w * sc);
}

__global__ __launch_bounds__(512) void k_lb(const float* __restrict__ top_s, float* __restrict__ lb_out) {
    __shared__ float sums[8];
    const int w = threadIdx.x >> 6, lane = threadIdx.x & 63;
    float s = 0.f;
    for (int c = lane; c < CAP; c += 64) s += top_s[w * CAP + c];
#pragma unroll
    for (int off = 32; off; off >>= 1) s += __shfl_xor(s, off);
    if (lane == 0) sums[w] = s;
    __syncthreads();
    if (threadIdx.x == 0) {
        float mean = 0.f, load[8];
#pragma unroll
        for (int e2 = 0; e2 < 8; e2++) { load[e2] = sums[e2] * (1.f / 4096.f); mean += load[e2]; }
        mean *= 0.125f;
        float var = 0.f;
#pragma unroll
        for (int e2 = 0; e2 < 8; e2++) { const float d = load[e2] - mean; var += d * d; }
        lb_out[0] = var * (1.f / 7.f) * 8.f;
    }
}

__global__ void k_fin(const float* __restrict__ lb, float* __restrict__ dst) {
    if (threadIdx.x == 0 && blockIdx.x == 0) dst[0] = lb[0] + lb[1];
}

extern "C" void kernel_launch(void* const* d_in, const int* in_sizes, int n_in,
                              void* d_out, int out_size, void* d_ws, size_t ws_size,
                              hipStream_t stream)
{
    const int*   ids_raw = (const int*)d_in[0];
    const float* mask  = (const float*)d_in[1];
    const float* embw  = (const float*)d_in[2];
    const float* ln1g  = (const float*)d_in[3];
    const float* ln1b  = (const float*)d_in[4];
    const float* qw    = (const float*)d_in[5];
    const float* kw    = (const float*)d_in[6];
    const float* vw    = (const float*)d_in[7];
    const float* ow    = (const float*)d_in[8];
    const float* ln2g  = (const float*)d_in[9];
    const float* ln2b  = (const float*)d_in[10];
    const float* gw    = (const float*)d_in[11];
    const float* w1    = (const float*)d_in[12];
    const float* b1    = (const float*)d_in[13];
    const float* w2    = (const float*)d_in[14];
    const float* b2    = (const float*)d_in[15];
    const float* lnfg  = (const float*)d_in[16];
    const float* lnfb  = (const float*)d_in[17];
    const float* headw = (const float*)d_in[18];
    float* out = (float*)d_out;

    char* wsb = (char*)d_ws;
    size_t off = 0;
    auto alloc = [&](size_t bytes) -> void* {
        off = (off + 255) & ~(size_t)255;
        void* p = wsb + off;
        off += bytes;
        return p;
    };
    float* h0  = (float*)alloc((size_t)TT * HH * 4);
    float* h1b = (float*)alloc((size_t)TT * HH * 4);
    float* hn  = (float*)alloc((size_t)TT * HH * 4);
    float* q   = (float*)alloc((size_t)TT * HH * 4);
    float* kf  = (float*)alloc((size_t)TT * HDIM * 4);
    float* vf  = (float*)alloc((size_t)TT * HDIM * 4);
    float* scoresT = (float*)alloc((size_t)NEXP * TT * 4);
    int*   idsn    = (int*)alloc((size_t)TT * 4);
    int*   top_i   = (int*)alloc((size_t)NEXP * CAP * 4);
    float* top_s   = (float*)alloc((size_t)NEXP * CAP * 4);
    float* lb      = (float*)alloc(64);
    if (off > ws_size) return;

    // optional bf16 head buffers (ws-gated; bit-identical results either path)
    unsigned short* hnb = (unsigned short*)alloc((size_t)TT * HH * 2);
    unsigned short* hwb = (unsigned short*)alloc((size_t)VOCAB * HH * 2);
    const bool bighead = (off <= ws_size);

    char* outb = (char*)d_out;
    size_t ooff = 0;
    auto oalloc = [&](size_t bytes) -> void* {
        ooff = (ooff + 255) & ~(size_t)255;
        void* p = outb + ooff;
        ooff += bytes;
        return p;
    };
    float* xg   = (float*)oalloc((size_t)NEXP * CAP * HH * 4);
    float* act  = (float*)oalloc((size_t)NEXP * CAP * FDIM * 4);
    float* oute = (float*)oalloc((size_t)NEXP * CAP * HH * 4);

    k_ids<<<16, 256, 0, stream>>>(ids_raw, idsn);
    k_embed<<<TT, 192, 0, stream>>>(idsn, embw, h0);

    float* hc = h0;
    float* ho = h1b;
    for (int l = 0; l < 2; l++) {
        k_ln<<<TT, 64, 0, stream>>>(hc, ln1g + l * HH, ln1b + l * HH, hn);
        k_qkv<<<dim3(7, TT/128), 256, 0, stream>>>(
            hn, qw + (size_t)l * HH * HH, kw + (size_t)l * HDIM * HH, vw + (size_t)l * HDIM * HH,
            q, kf, vf);
        k_fattn<<<2 * NHEAD * (SEQ / 64), 256, 0, stream>>>(q, kf, vf, mask, hn);
        k_sgemm128<true,false,false,true>
            <<<dim3(TT/128, HH/128, 1), 256, 0, stream>>>(
            hn, ow + (size_t)l * HH * HH, nullptr, hc, ho, TT, HH, HH, 0, 0, 0, 0);
        k_ln<<<TT, 64, 0, stream>>>(ho, ln2g + l * HH, ln2b + l * HH, hn);
        k_gate<<<TT, 64, 0, stream>>>(hn, gw + (size_t)l * NEXP * HH, scoresT);
        k_topk<<<NEXP, 1024, 0, stream>>>(scoresT, top_i, top_s);
        k_gather<<<NEXP * CAP, 192, 0, stream>>>(top_i, hn, xg);
        if (l == 1) {
            k_gemm<false,false,true,true,false,float,float>
                <<<dim3(FDIM/64, CAP/64, NEXP), 256, 0, stream>>>(
                xg, w1 + (size_t)l * NEXP * HH * FDIM, b1 + (size_t)l * NEXP * FDIM, nullptr, act,
                CAP, FDIM, HH, (long long)CAP * HH, (long long)HH * FDIM, FDIM, (long long)CAP * FDIM);
            k_gemm<false,false,true,false,false,float,float>
                <<<dim3(HH/64, CAP/64, NEXP), 256, 0, stream>>>(
                act, w2 + (size_t)l * NEXP * FDIM * HH, b2 + (size_t)l * NEXP * HH, nullptr, oute,
                CAP, HH, FDIM, (long long)CAP * FDIM, (long long)FDIM * HH, HH, (long long)CAP * HH);
        } else {
            k_sgemm128<false,true,true,false>
                <<<dim3(CAP/128, FDIM/128, NEXP), 256, 0, stream>>>(
                xg, w1 + (size_t)l * NEXP * HH * FDIM, b1 + (size_t)l * NEXP * FDIM, nullptr, act,
                CAP, FDIM, HH, (long long)CAP * HH, (long long)HH * FDIM, FDIM, (long long)CAP * FDIM);
            k_sgemm128<false,true,false,false>
                <<<dim3(CAP/128, HH/128, NEXP), 256, 0, stream>>>(
                act, w2 + (size_t)l * NEXP * FDIM * HH, b2 + (size_t)l * NEXP * HH, nullptr, oute,
                CAP, HH, FDIM, (long long)CAP * FDIM, (long long)FDIM * HH, HH, (long long)CAP * HH);
        }
        k_scatter<<<NEXP * CAP, 192, 0, stream>>>(top_i, top_s, oute, ho);
        k_lb<<<1, 512, 0, stream>>>(top_s, lb + l);
        float* tmp = hc; hc = ho; ho = tmp;
    }
    k_ln<<<TT, 64, 0, stream>>>(hc, lnfg, lnfb, hn);
    if (bighead) {
        k_tobf<<<(TT * HH / 8 + 255) / 256, 256, 0, stream>>>(hn, hnb, TT * HH / 8);
        k_tobf<<<(VOCAB * HH / 8 + 255) / 256, 256, 0, stream>>>(headw, hwb, VOCAB * HH / 8);
        k_gemm128g<<<dim3(TT/128, VOCAB/128, 1), 256, 0, stream>>>(hnb, hwb, out, TT, VOCAB, HH);
    } else {
        k_gemm128<<<dim3(TT/128, VOCAB/128, 1), 256, 0, stream>>>(hn, headw, out, TT, VOCAB, HH);
    }
    k_fin<<<1, 64, 0, stream>>>(lb, out + (size_t)TT * VOCAB);
}